// Round 2
// 2066.009 us; speedup vs baseline: 1.4549x; 1.4549x over previous
//
#include <hip/hip_runtime.h>

// Qwen3 MoE decoder layer, MI355X. Round 7: 64x64-tile fp32 flash attention,
// de-risked to exactly 64 KB static LDS (Qs 32KB + time-shared KVs 32KB;
// P kept in registers, broadcast via intra-wave __shfl). K/V tiles are
// register-prefetched (async-stage) so the K->V LDS time-share doesn't
// serialize against global latency. Pair-balanced grid (qt, 15-qt) ->
// uniform 17 k-tiles/block, 256 blocks = 1/CU. Everything else unchanged
// from the 3006-us baseline.

namespace {

constexpr int cB = 2, cS = 1024, cH = 2048;
constexpr int cNH = 16, cNKV = 4, cHD = 128;
constexpr int cE = 8, cI = 768;
constexpr int cT = cB * cS;        // 2048 tokens
constexpr int cDq = cNH * cHD;     // 2048
constexpr int cDkv = cNKV * cHD;   // 512
constexpr float cEPS = 1e-6f;
constexpr float cSCALE = 0.08838834764831845f;  // HD^-0.5
constexpr int cQT = cS / 64;       // 16 q-tiles per (b,h)

// ---------------- RMSNorm (fp32) ----------------
__global__ __launch_bounds__(256) void k_rmsnorm(
    const float* __restrict__ xin, const float* __restrict__ w,
    float* __restrict__ y) {
  int t = blockIdx.x, tid = threadIdx.x;
  __shared__ float red[256];
  const float* xr = xin + (size_t)t * cH;
  float xv[8];
  float ss = 0.f;
#pragma unroll
  for (int i = 0; i < 8; ++i) {
    xv[i] = xr[tid + i * 256];
    ss += xv[i] * xv[i];
  }
  red[tid] = ss;
  __syncthreads();
  for (int s = 128; s > 0; s >>= 1) {
    if (tid < s) red[tid] += red[tid + s];
    __syncthreads();
  }
  float inv = rsqrtf(red[0] / (float)cH + cEPS);
#pragma unroll
  for (int i = 0; i < 8; ++i)
    y[(size_t)t * cH + tid + i * 256] = xv[i] * inv * w[tid + i * 256];
}

// ---------- C[m,n] = sum_k A[m,k]*W[n,k] (+ fp32 residual) -----------------
// 64x64 tile, BK=16, 256 threads, 4x4 acc/thread. All fp32.
template <bool ADD_RESID>
__global__ __launch_bounds__(256) void k_gemm_xwT(
    const float* __restrict__ A, const float* __restrict__ W,
    float* __restrict__ C, const float* __restrict__ resid,
    int M, int N, int K) {
  __shared__ float As[16][64];
  __shared__ float Bs[16][64];
  int tid = threadIdx.x;
  int tx = tid & 15, ty = tid >> 4;
  int mBase = blockIdx.y * 64, nBase = blockIdx.x * 64;
  int idx = tid * 4;
  int lm = idx >> 4, lk = idx & 15;  // lm 0..63, lk in {0,4,8,12}
  float acc[4][4] = {};
  const float* aptr = A + (size_t)(mBase + lm) * K;
  const float* wptr = W + (size_t)(nBase + lm) * K;
  for (int k0 = 0; k0 < K; k0 += 16) {
    float4 av = *(const float4*)(aptr + k0 + lk);
    float4 wv = *(const float4*)(wptr + k0 + lk);
    As[lk + 0][lm] = av.x;
    As[lk + 1][lm] = av.y;
    As[lk + 2][lm] = av.z;
    As[lk + 3][lm] = av.w;
    Bs[lk + 0][lm] = wv.x;
    Bs[lk + 1][lm] = wv.y;
    Bs[lk + 2][lm] = wv.z;
    Bs[lk + 3][lm] = wv.w;
    __syncthreads();
#pragma unroll
    for (int k = 0; k < 16; ++k) {
      float a[4], b[4];
#pragma unroll
      for (int i = 0; i < 4; ++i) a[i] = As[k][ty * 4 + i];
#pragma unroll
      for (int j = 0; j < 4; ++j) b[j] = Bs[k][tx * 4 + j];
#pragma unroll
      for (int i = 0; i < 4; ++i)
#pragma unroll
        for (int j = 0; j < 4; ++j) acc[i][j] += a[i] * b[j];
    }
    __syncthreads();
  }
#pragma unroll
  for (int i = 0; i < 4; ++i) {
    int m = mBase + ty * 4 + i;
#pragma unroll
    for (int j = 0; j < 4; ++j) {
      int n = nBase + tx * 4 + j;
      float v = acc[i][j];
      if (ADD_RESID) v += resid[(size_t)m * N + n];
      C[(size_t)m * N + n] = v;
    }
  }
}

// ---------------- per-head RMSNorm + RoPE on q and k (in place) ------------
__global__ __launch_bounds__(128) void k_qknorm_rope(
    float* qbuf, float* kbuf,
    const float* __restrict__ qw, const float* __restrict__ kw,
    const float* __restrict__ cosb, const float* __restrict__ sinb,
    int cosBS) {
  int t = blockIdx.x, head = blockIdx.y, d = threadIdx.x;
  float* buf;
  const float* w;
  if (head < cNH) {
    buf = qbuf + (size_t)t * cDq + head * cHD;
    w = qw;
  } else {
    buf = kbuf + (size_t)t * cDkv + (head - cNH) * cHD;
    w = kw;
  }
  __shared__ float xs[cHD];
  __shared__ float red[cHD];
  float x = buf[d];
  xs[d] = x;
  red[d] = x * x;
  __syncthreads();
  for (int s = 64; s > 0; s >>= 1) {
    if (d < s) red[d] += red[d + s];
    __syncthreads();
  }
  float inv = rsqrtf(red[0] / (float)cHD + cEPS);
  int od = d ^ 64;  // rotate_half partner
  float y = x * inv * w[d];
  float yo = xs[od] * inv * w[od];
  float rot = (d < 64) ? -yo : yo;
  size_t ci = (size_t)(t % cosBS) * cHD + d;
  buf[d] = y * cosb[ci] + rot * sinb[ci];
}

// ---------------- tiled causal attention (fp32, online softmax) ------------
// Block = (q-tile-pair, h, b), 256 threads. TQ=TK=64, HD=128.
// LDS (64 KB total): Qs 32KB + KVs 32KB time-shared (K for QK^T, V for PV),
// both XOR-swizzled so b128 reads are bank-conflict-free. P stays in
// registers; PV broadcasts it intra-wave via __shfl (ty-group = 16
// contiguous lanes of one wave). K/V tiles register-prefetched so global
// latency hides under the previous compute phase.
// Thread (tx=tid&15, ty=tid>>4): S rows ty*4+i, cols tx*4+j;
// O rows ty*4+i, cols {tx*4+j, 64+tx*4+j}.
__device__ __forceinline__ int swzKQ(int r, int cb) {  // cb: float4 block 0..31
  return r * 128 + ((cb ^ ((r >> 2) & 7)) << 2);
}

__global__ __launch_bounds__(256) void k_attn_tiled(
    float* qc, const float* __restrict__ k, const float* __restrict__ v) {
  __shared__ __align__(16) float Qs[64 * 128];   // 32 KB
  __shared__ __align__(16) float KVs[64 * 128];  // 32 KB, K then V per tile
  int pidx = blockIdx.x, h = blockIdx.y, b = blockIdx.z;
  int kvh = h >> 2;  // rep = NH/NKV = 4
  int tid = threadIdx.x;
  int tx = tid & 15, ty = tid >> 4;
  const float* kbase = k + (size_t)b * cS * cDkv + kvh * cHD;
  const float* vbase = v + (size_t)b * cS * cDkv + kvh * cHD;
  float* qhbase = qc + (size_t)b * cS * cDq + h * cHD;

  for (int half = 0; half < 2; ++half) {
    int qt = half ? (cQT - 1 - pidx) : pidx;  // pair (p, 15-p): 17 k-tiles
    // ---- load Q tile (scaled) into swizzled LDS ----
#pragma unroll
    for (int ch = 0; ch < 8; ++ch) {
      int idx = tid + ch * 256;
      int r = idx >> 5, cb = idx & 31;
      float4 qv = *(const float4*)(qhbase + (size_t)(qt * 64 + r) * cDq + cb * 4);
      qv.x *= cSCALE; qv.y *= cSCALE; qv.z *= cSCALE; qv.w *= cSCALE;
      *(float4*)&Qs[swzKQ(r, cb)] = qv;
    }
    // ---- prefetch K tile 0 into registers ----
    float4 kreg[8];
#pragma unroll
    for (int ch = 0; ch < 8; ++ch) {
      int idx = tid + ch * 256;
      int r = idx >> 5, cb = idx & 31;
      kreg[ch] = *(const float4*)(kbase + (size_t)r * cDkv + cb * 4);
    }
    float m[4], l[4], O[4][8];
#pragma unroll
    for (int i = 0; i < 4; ++i) {
      m[i] = -1e30f;
      l[i] = 0.f;
#pragma unroll
      for (int j = 0; j < 8; ++j) O[i][j] = 0.f;
    }
    __syncthreads();  // Qs visible (also: prior-half PV reads of KVs done)

    for (int kt = 0; kt <= qt; ++kt) {
      // ---- K tile: registers -> LDS ----
#pragma unroll
      for (int ch = 0; ch < 8; ++ch) {
        int idx = tid + ch * 256;
        *(float4*)&KVs[swzKQ(idx >> 5, idx & 31)] = kreg[ch];
      }
      __syncthreads();
      // ---- issue V loads now; consumed after QK^T (latency hidden) ----
      float4 vreg[8];
#pragma unroll
      for (int ch = 0; ch < 8; ++ch) {
        int idx = tid + ch * 256;
        int r = idx >> 5, cb = idx & 31;
        vreg[ch] = *(const float4*)(vbase + (size_t)(kt * 64 + r) * cDkv + cb * 4);
      }
      // ---- S = Q K^T (4x4 per thread) ----
      float acc[4][4] = {};
#pragma unroll 8
      for (int dblk = 0; dblk < 32; ++dblk) {
        float4 a4[4], b4[4];
#pragma unroll
        for (int i = 0; i < 4; ++i)
          a4[i] = *(const float4*)&Qs[swzKQ(ty * 4 + i, dblk)];
#pragma unroll
        for (int j = 0; j < 4; ++j)
          b4[j] = *(const float4*)&KVs[swzKQ(tx * 4 + j, dblk)];
#pragma unroll
        for (int i = 0; i < 4; ++i)
#pragma unroll
          for (int j = 0; j < 4; ++j)
            acc[i][j] += a4[i].x * b4[j].x + a4[i].y * b4[j].y +
                         a4[i].z * b4[j].z + a4[i].w * b4[j].w;
      }
      // ---- causal mask: only the diagonal tile has masked entries ----
      if (kt == qt) {
#pragma unroll
        for (int i = 0; i < 4; ++i)
#pragma unroll
          for (int j = 0; j < 4; ++j)
            if (tx * 4 + j > ty * 4 + i) acc[i][j] = -1e30f;
      }
      // ---- online softmax update (row stats via 16-lane butterflies) ----
      float ps[4][4];
#pragma unroll
      for (int i = 0; i < 4; ++i) {
        float rm = fmaxf(fmaxf(acc[i][0], acc[i][1]), fmaxf(acc[i][2], acc[i][3]));
#pragma unroll
        for (int msk = 1; msk < 16; msk <<= 1) rm = fmaxf(rm, __shfl_xor(rm, msk));
        float nm = fmaxf(m[i], rm);
        float sc_ = __expf(m[i] - nm);  // m=-1e30 first pass -> 0
        float rs = 0.f;
#pragma unroll
        for (int j = 0; j < 4; ++j) {
          ps[i][j] = __expf(acc[i][j] - nm);
          rs += ps[i][j];
        }
#pragma unroll
        for (int msk = 1; msk < 16; msk <<= 1) rs += __shfl_xor(rs, msk);
        l[i] = l[i] * sc_ + rs;
        m[i] = nm;
#pragma unroll
        for (int j = 0; j < 8; ++j) O[i][j] *= sc_;
      }
      __syncthreads();  // all QK^T reads of KVs (=K) done
      // ---- V tile: registers -> LDS (compiler waits vmcnt here) ----
#pragma unroll
      for (int ch = 0; ch < 8; ++ch) {
        int idx = tid + ch * 256;
        *(float4*)&KVs[swzKQ(idx >> 5, idx & 31)] = vreg[ch];
      }
      __syncthreads();
      // ---- prefetch next K tile; latency hidden under PV ----
      if (kt < qt) {
#pragma unroll
        for (int ch = 0; ch < 8; ++ch) {
          int idx = tid + ch * 256;
          int r = idx >> 5, cb = idx & 31;
          kreg[ch] =
              *(const float4*)(kbase + (size_t)((kt + 1) * 64 + r) * cDkv + cb * 4);
        }
      }
      // ---- O += P V; P broadcast from registers via intra-wave shfl ----
#pragma unroll
      for (int kc = 0; kc < 16; ++kc) {
        float4 va[4], vb[4];
#pragma unroll
        for (int q = 0; q < 4; ++q) {
          int kk = kc * 4 + q;
          va[q] = *(const float4*)&KVs[swzKQ(kk, tx)];
          vb[q] = *(const float4*)&KVs[swzKQ(kk, tx + 16)];
        }
        int src = (tid & 48) | kc;  // lane holding P[row][kc*4+q] (q = reg idx)
#pragma unroll
        for (int q = 0; q < 4; ++q)
#pragma unroll
          for (int i = 0; i < 4; ++i) {
            float pq = __shfl(ps[i][q], src);
            O[i][0] += pq * va[q].x;
            O[i][1] += pq * va[q].y;
            O[i][2] += pq * va[q].z;
            O[i][3] += pq * va[q].w;
            O[i][4] += pq * vb[q].x;
            O[i][5] += pq * vb[q].y;
            O[i][6] += pq * vb[q].z;
            O[i][7] += pq * vb[q].w;
          }
      }
      __syncthreads();  // PV reads of KVs done before next K write
    }  // kt
    // ---- epilogue: ctx = O / l, written back in place over q ----
#pragma unroll
    for (int i = 0; i < 4; ++i) {
      float inv = 1.f / l[i];
      float* orow = qhbase + (size_t)(qt * 64 + ty * 4 + i) * cDq;
      *(float4*)(orow + tx * 4) =
          make_float4(O[i][0] * inv, O[i][1] * inv, O[i][2] * inv, O[i][3] * inv);
      *(float4*)(orow + 64 + tx * 4) =
          make_float4(O[i][4] * inv, O[i][5] * inv, O[i][6] * inv, O[i][7] * inv);
    }
  }  // half
}

// ---------------- router: logits, top-2, compaction ------------------------
__global__ void k_zero_counts(int* __restrict__ counts) {
  if (threadIdx.x < cE) counts[threadIdx.x] = 0;
}

__global__ __launch_bounds__(64) void k_route(
    const float* __restrict__ x2, const float* __restrict__ gw,
    float* __restrict__ topw, int* __restrict__ counts, int* __restrict__ lists) {
  int t = blockIdx.x, lane = threadIdx.x;
  float acc[cE];
#pragma unroll
  for (int e = 0; e < cE; ++e) acc[e] = 0.f;
  const float* xr = x2 + (size_t)t * cH;
  for (int hh = lane; hh < cH; hh += 64) {
    float xv = xr[hh];
#pragma unroll
    for (int e = 0; e < cE; ++e) acc[e] += xv * gw[e * cH + hh];
  }
#pragma unroll
  for (int e = 0; e < cE; ++e)
    for (int off = 32; off > 0; off >>= 1) acc[e] += __shfl_down(acc[e], off);
  if (lane == 0) {
    int i0 = 0;
    float l0 = acc[0];
#pragma unroll
    for (int e = 1; e < cE; ++e)
      if (acc[e] > l0) { l0 = acc[e]; i0 = e; }
    int i1 = -1;
    float l1 = -1e30f;
#pragma unroll
    for (int e = 0; e < cE; ++e)
      if (e != i0 && acc[e] > l1) { l1 = acc[e]; i1 = e; }
    if (i1 < 0) { i1 = (i0 + 1) & 7; l1 = l0; }  // NaN-safe
    float r = expf(l1 - l0);  // top-2 softmax renorm == sigmoid of gap
    topw[t * 2 + 0] = 1.f / (1.f + r);
    topw[t * 2 + 1] = r / (1.f + r);
    int p0 = atomicAdd(&counts[i0], 1);
    lists[i0 * cT + p0] = t * 2;      // entry = token*2 + slot
    int p1 = atomicAdd(&counts[i1], 1);
    lists[i1 * cT + p1] = t * 2 + 1;
  }
}

// ---------------- grouped gate/up GEMM + SiLU*up*weight --------------------
__global__ __launch_bounds__(256) void k_moe_gateup(
    const float* __restrict__ X, const float* __restrict__ Wg,
    const float* __restrict__ Wu, const int* __restrict__ counts,
    const int* __restrict__ lists, const float* __restrict__ topw,
    float* __restrict__ act) {
  int e = blockIdx.z;
  int cnt = counts[e];
  int mBase = blockIdx.y * 64;
  if (mBase >= cnt) return;
  int nBase = blockIdx.x * 64;
  __shared__ float As[16][64], Gs[16][64], Us[16][64];
  __shared__ int rowE[64];
  int tid = threadIdx.x;
  int tx = tid & 15, ty = tid >> 4;
  if (tid < 64) {
    int r = mBase + tid;
    rowE[tid] = (r < cnt) ? lists[e * cT + r] : -1;
  }
  __syncthreads();
  int idx = tid * 4, lm = idx >> 4, lk = idx & 15;
  int entL = rowE[lm];
  const float* arow = X + (size_t)((entL >= 0) ? (entL >> 1) : 0) * cH;
  const float* wg = Wg + (size_t)e * cI * cH + (size_t)(nBase + lm) * cH;
  const float* wu = Wu + (size_t)e * cI * cH + (size_t)(nBase + lm) * cH;
  float accg[4][4] = {}, accu[4][4] = {};
  for (int k0 = 0; k0 < cH; k0 += 16) {
    float4 av = *(const float4*)(arow + k0 + lk);
    float4 gv = *(const float4*)(wg + k0 + lk);
    float4 uv = *(const float4*)(wu + k0 + lk);
    As[lk + 0][lm] = av.x;
    As[lk + 1][lm] = av.y;
    As[lk + 2][lm] = av.z;
    As[lk + 3][lm] = av.w;
    Gs[lk + 0][lm] = gv.x;
    Gs[lk + 1][lm] = gv.y;
    Gs[lk + 2][lm] = gv.z;
    Gs[lk + 3][lm] = gv.w;
    Us[lk + 0][lm] = uv.x;
    Us[lk + 1][lm] = uv.y;
    Us[lk + 2][lm] = uv.z;
    Us[lk + 3][lm] = uv.w;
    __syncthreads();
#pragma unroll
    for (int k = 0; k < 16; ++k) {
      float a[4], g[4], u[4];
#pragma unroll
      for (int i = 0; i < 4; ++i) a[i] = As[k][ty * 4 + i];
#pragma unroll
      for (int j = 0; j < 4; ++j) {
        g[j] = Gs[k][tx * 4 + j];
        u[j] = Us[k][tx * 4 + j];
      }
#pragma unroll
      for (int i = 0; i < 4; ++i)
#pragma unroll
        for (int j = 0; j < 4; ++j) {
          accg[i][j] += a[i] * g[j];
          accu[i][j] += a[i] * u[j];
        }
    }
    __syncthreads();
  }
#pragma unroll
  for (int i = 0; i < 4; ++i) {
    int r = mBase + ty * 4 + i;
    if (r >= cnt) continue;
    int ent = rowE[ty * 4 + i];
    float w = topw[ent];
#pragma unroll
    for (int j = 0; j < 4; ++j) {
      int n = nBase + tx * 4 + j;
      float g = accg[i][j], u = accu[i][j];
      float sg = g / (1.f + expf(-g));  // SiLU
      act[(size_t)ent * cI + n] = sg * u * w;
    }
  }
}

// ---------------- grouped down GEMM, atomicAdd into residual (d_out) -------
__global__ __launch_bounds__(256) void k_moe_down(
    const float* __restrict__ act, const float* __restrict__ Wd,
    const int* __restrict__ counts, const int* __restrict__ lists,
    float* __restrict__ F) {
  int e = blockIdx.z;
  int cnt = counts[e];
  int mBase = blockIdx.y * 64;
  if (mBase >= cnt) return;
  int nBase = blockIdx.x * 64;
  __shared__ float As[16][64], Bs[16][64];
  __shared__ int rowE[64];
  int tid = threadIdx.x;
  int tx = tid & 15, ty = tid >> 4;
  if (tid < 64) {
    int r = mBase + tid;
    rowE[tid] = (r < cnt) ? lists[e * cT + r] : -1;
  }
  __syncthreads();
  int idx = tid * 4, lm = idx >> 4, lk = idx & 15;
  int entL = rowE[lm];
  const float* arow = act + (size_t)((entL >= 0) ? entL : 0) * cI;
  const float* wrow = Wd + (size_t)e * cH * cI + (size_t)(nBase + lm) * cI;
  float acc[4][4] = {};
  for (int k0 = 0; k0 < cI; k0 += 16) {
    float4 av = *(const float4*)(arow + k0 + lk);
    float4 wv = *(const float4*)(wrow + k0 + lk);
    As[lk + 0][lm] = av.x;
    As[lk + 1][lm] = av.y;
    As[lk + 2][lm] = av.z;
    As[lk + 3][lm] = av.w;
    Bs[lk + 0][lm] = wv.x;
    Bs[lk + 1][lm] = wv.y;
    Bs[lk + 2][lm] = wv.z;
    Bs[lk + 3][lm] = wv.w;
    __syncthreads();
#pragma unroll
    for (int k = 0; k < 16; ++k) {
      float a[4], b[4];
#pragma unroll
      for (int i = 0; i < 4; ++i) a[i] = As[k][ty * 4 + i];
#pragma unroll
      for (int j = 0; j < 4; ++j) b[j] = Bs[k][tx * 4 + j];
#pragma unroll
      for (int i = 0; i < 4; ++i)
#pragma unroll
        for (int j = 0; j < 4; ++j) acc[i][j] += a[i] * b[j];
    }
    __syncthreads();
  }
#pragma unroll
  for (int i = 0; i < 4; ++i) {
    int r = mBase + ty * 4 + i;
    if (r >= cnt) continue;
    int t = rowE[ty * 4 + i] >> 1;
#pragma unroll
    for (int j = 0; j < 4; ++j)
      atomicAdd(&F[(size_t)t * cH + nBase + tx * 4 + j], acc[i][j]);
  }
}

}  // namespace

extern "C" void kernel_launch(void* const* d_in, const int* in_sizes, int n_in,
                              void* d_out, int out_size, void* d_ws, size_t ws_size,
                              hipStream_t stream) {
  (void)n_in; (void)out_size; (void)ws_size;
  // Defensive: if the start_pos scalar was dropped from d_in, shift indices.
  int off = (in_sizes[1] == 1) ? 0 : -1;
  const float* hidden   = (const float*)d_in[0];
  const float* cosb     = (const float*)d_in[2 + off];
  const float* sinb     = (const float*)d_in[3 + off];
  // d_in[4+off] = attention_mask (exactly causal; handled structurally)
  const float* w_q      = (const float*)d_in[5 + off];
  const float* w_k      = (const float*)d_in[6 + off];
  const float* w_v      = (const float*)d_in[7 + off];
  const float* w_o      = (const float*)d_in[8 + off];
  const float* q_norm_w = (const float*)d_in[9 + off];
  const float* k_norm_w = (const float*)d_in[10 + off];
  const float* ln1_w    = (const float*)d_in[11 + off];
  const float* ln2_w    = (const float*)d_in[12 + off];
  const float* gate_w   = (const float*)d_in[13 + off];
  const float* w_gate_e = (const float*)d_in[14 + off];
  const float* w_up_e   = (const float*)d_in[15 + off];
  const float* w_down_e = (const float*)d_in[16 + off];
  float* F = (float*)d_out;             // fp32 output == residual accumulator
  int cosBS = in_sizes[2 + off] / cHD;  // 2048 if (B,S,HD)

  // Workspace (floats), ~40.1 MB:
  float* ws = (float*)d_ws;
  float* xbuf  = ws;                        // cT*cH (16MB): ln1 out -> ln2 out
  float* qcbuf = xbuf + (size_t)cT * cH;    // cT*cDq (16MB): q -> ctx -> act
  float* kbuf  = qcbuf + (size_t)cT * cDq;  // cT*cDkv (4MB)
  float* vbuf  = kbuf + (size_t)cT * cDkv;  // cT*cDkv (4MB)
  float* topw  = vbuf + (size_t)cT * cDkv;  // cT*2
  int* counts  = (int*)(topw + (size_t)cT * 2);
  int* lists   = counts + cE;               // cE*cT
  float* act   = qcbuf;                     // reuse after O-proj consumed ctx

  k_rmsnorm<<<cT, 256, 0, stream>>>(hidden, ln1_w, xbuf);
  k_gemm_xwT<false><<<dim3(cDq / 64, cT / 64), 256, 0, stream>>>(
      xbuf, w_q, qcbuf, nullptr, cT, cDq, cH);
  k_gemm_xwT<false><<<dim3(cDkv / 64, cT / 64), 256, 0, stream>>>(
      xbuf, w_k, kbuf, nullptr, cT, cDkv, cH);
  k_gemm_xwT<false><<<dim3(cDkv / 64, cT / 64), 256, 0, stream>>>(
      xbuf, w_v, vbuf, nullptr, cT, cDkv, cH);
  k_qknorm_rope<<<dim3(cT, cNH + cNKV), 128, 0, stream>>>(
      qcbuf, kbuf, q_norm_w, k_norm_w, cosb, sinb, cosBS);
  k_attn_tiled<<<dim3(cQT / 2, cNH, cB), 256, 0, stream>>>(qcbuf, kbuf, vbuf);
  k_gemm_xwT<true><<<dim3(cH / 64, cT / 64), 256, 0, stream>>>(
      qcbuf, w_o, F, hidden, cT, cH, cH);
  k_rmsnorm<<<cT, 256, 0, stream>>>(F, ln2_w, xbuf);
  k_zero_counts<<<1, 64, 0, stream>>>(counts);
  k_route<<<cT, 64, 0, stream>>>(xbuf, gate_w, topw, counts, lists);
  k_moe_gateup<<<dim3(cI / 64, cT / 64, cE), 256, 0, stream>>>(
      xbuf, w_gate_e, w_up_e, counts, lists, topw, act);
  k_moe_down<<<dim3(cH / 64, cT / 64, cE), 256, 0, stream>>>(
      act, w_down_e, counts, lists, F);
}

// Round 4
// 1502.189 us; speedup vs baseline: 2.0010x; 1.3753x over previous
//
#include <hip/hip_runtime.h>

// Qwen3 MoE decoder layer, MI355X. Round 9: R8 failed (absmax 0.617) --
// diagnosis: bf16 noise upstream of the router flips top-2 expert choices
// (discrete error ~0.15-0.6 on flipped tokens). Fix/bisect: pre-router chain
// (QKV/attn/O) reverted to the PASSING R7 fp32 kernels; bf16 MFMA
// (mfma_f32_16x16x32_bf16, RNE conversion, fp32 acc) applied ONLY to the
// post-routing MoE expert GEMMs (gate/up fused + down). If this fails big,
// the MFMA template is implicated; if it passes, template is proven for a
// later EFT-bf16 attack on the dense GEMMs.

namespace {

constexpr int cB = 2, cS = 1024, cH = 2048;
constexpr int cNH = 16, cNKV = 4, cHD = 128;
constexpr int cE = 8, cI = 768;
constexpr int cT = cB * cS;        // 2048 tokens
constexpr int cDq = cNH * cHD;     // 2048
constexpr int cDkv = cNKV * cHD;   // 512
constexpr float cEPS = 1e-6f;
constexpr float cSCALE = 0.08838834764831845f;  // HD^-0.5
constexpr int cQT = cS / 64;       // 16 q-tiles per (b,h)

typedef __attribute__((ext_vector_type(8))) short bf16x8;
typedef __attribute__((ext_vector_type(4))) float f32x4;

// fp32 -> bf16 round-to-nearest-even, packed pair (f0 low, f1 high)
__device__ __forceinline__ unsigned pack2(float f0, float f1) {
  unsigned u0 = __float_as_uint(f0), u1 = __float_as_uint(f1);
  unsigned r0 = (u0 + (0x7FFFu + ((u0 >> 16) & 1u))) >> 16;
  unsigned r1 = (u1 + (0x7FFFu + ((u1 >> 16) & 1u))) & 0xFFFF0000u;
  return r0 | r1;
}
__device__ __forceinline__ uint4 pack8(const float4& a, const float4& b) {
  return make_uint4(pack2(a.x, a.y), pack2(a.z, a.w),
                    pack2(b.x, b.y), pack2(b.z, b.w));
}

// ---------------- RMSNorm (fp32) ----------------
__global__ __launch_bounds__(256) void k_rmsnorm(
    const float* __restrict__ xin, const float* __restrict__ w,
    float* __restrict__ y) {
  int t = blockIdx.x, tid = threadIdx.x;
  __shared__ float red[256];
  const float* xr = xin + (size_t)t * cH;
  float xv[8];
  float ss = 0.f;
#pragma unroll
  for (int i = 0; i < 8; ++i) {
    xv[i] = xr[tid + i * 256];
    ss += xv[i] * xv[i];
  }
  red[tid] = ss;
  __syncthreads();
  for (int s = 128; s > 0; s >>= 1) {
    if (tid < s) red[tid] += red[tid + s];
    __syncthreads();
  }
  float inv = rsqrtf(red[0] / (float)cH + cEPS);
#pragma unroll
  for (int i = 0; i < 8; ++i)
    y[(size_t)t * cH + tid + i * 256] = xv[i] * inv * w[tid + i * 256];
}

// ---------- C[m,n] = sum_k A[m,k]*W[n,k] (+ fp32 residual), fp32 VALU ------
template <bool ADD_RESID>
__global__ __launch_bounds__(256) void k_gemm_xwT(
    const float* __restrict__ A, const float* __restrict__ W,
    float* __restrict__ C, const float* __restrict__ resid,
    int M, int N, int K) {
  __shared__ float As[16][64];
  __shared__ float Bs[16][64];
  int tid = threadIdx.x;
  int tx = tid & 15, ty = tid >> 4;
  int mBase = blockIdx.y * 64, nBase = blockIdx.x * 64;
  int idx = tid * 4;
  int lm = idx >> 4, lk = idx & 15;  // lm 0..63, lk in {0,4,8,12}
  float acc[4][4] = {};
  const float* aptr = A + (size_t)(mBase + lm) * K;
  const float* wptr = W + (size_t)(nBase + lm) * K;
  for (int k0 = 0; k0 < K; k0 += 16) {
    float4 av = *(const float4*)(aptr + k0 + lk);
    float4 wv = *(const float4*)(wptr + k0 + lk);
    As[lk + 0][lm] = av.x;
    As[lk + 1][lm] = av.y;
    As[lk + 2][lm] = av.z;
    As[lk + 3][lm] = av.w;
    Bs[lk + 0][lm] = wv.x;
    Bs[lk + 1][lm] = wv.y;
    Bs[lk + 2][lm] = wv.z;
    Bs[lk + 3][lm] = wv.w;
    __syncthreads();
#pragma unroll
    for (int k = 0; k < 16; ++k) {
      float a[4], b[4];
#pragma unroll
      for (int i = 0; i < 4; ++i) a[i] = As[k][ty * 4 + i];
#pragma unroll
      for (int j = 0; j < 4; ++j) b[j] = Bs[k][tx * 4 + j];
#pragma unroll
      for (int i = 0; i < 4; ++i)
#pragma unroll
        for (int j = 0; j < 4; ++j) acc[i][j] += a[i] * b[j];
    }
    __syncthreads();
  }
#pragma unroll
  for (int i = 0; i < 4; ++i) {
    int m = mBase + ty * 4 + i;
#pragma unroll
    for (int j = 0; j < 4; ++j) {
      int n = nBase + tx * 4 + j;
      float v = acc[i][j];
      if (ADD_RESID) v += resid[(size_t)m * N + n];
      C[(size_t)m * N + n] = v;
    }
  }
}

// ---------------- per-head RMSNorm + RoPE on q and k (in place) ------------
__global__ __launch_bounds__(128) void k_qknorm_rope(
    float* qbuf, float* kbuf,
    const float* __restrict__ qw, const float* __restrict__ kw,
    const float* __restrict__ cosb, const float* __restrict__ sinb,
    int cosBS) {
  int t = blockIdx.x, head = blockIdx.y, d = threadIdx.x;
  float* buf;
  const float* w;
  if (head < cNH) {
    buf = qbuf + (size_t)t * cDq + head * cHD;
    w = qw;
  } else {
    buf = kbuf + (size_t)t * cDkv + (head - cNH) * cHD;
    w = kw;
  }
  __shared__ float xs[cHD];
  __shared__ float red[cHD];
  float x = buf[d];
  xs[d] = x;
  red[d] = x * x;
  __syncthreads();
  for (int s = 64; s > 0; s >>= 1) {
    if (d < s) red[d] += red[d + s];
    __syncthreads();
  }
  float inv = rsqrtf(red[0] / (float)cHD + cEPS);
  int od = d ^ 64;  // rotate_half partner
  float y = x * inv * w[d];
  float yo = xs[od] * inv * w[od];
  float rot = (d < 64) ? -yo : yo;
  size_t ci = (size_t)(t % cosBS) * cHD + d;
  buf[d] = y * cosb[ci] + rot * sinb[ci];
}

// ---------------- tiled causal attention (fp32, online softmax) ------------
__device__ __forceinline__ int swzKQ(int r, int cb) {  // cb: float4 block 0..31
  return r * 128 + ((cb ^ ((r >> 2) & 7)) << 2);
}

__global__ __launch_bounds__(256) void k_attn_tiled(
    float* qc, const float* __restrict__ k, const float* __restrict__ v) {
  __shared__ __align__(16) float Qs[64 * 128];   // 32 KB
  __shared__ __align__(16) float KVs[64 * 128];  // 32 KB, K then V per tile
  int pidx = blockIdx.x, h = blockIdx.y, b = blockIdx.z;
  int kvh = h >> 2;  // rep = NH/NKV = 4
  int tid = threadIdx.x;
  int tx = tid & 15, ty = tid >> 4;
  const float* kbase = k + (size_t)b * cS * cDkv + kvh * cHD;
  const float* vbase = v + (size_t)b * cS * cDkv + kvh * cHD;
  float* qhbase = qc + (size_t)b * cS * cDq + h * cHD;

  for (int half = 0; half < 2; ++half) {
    int qt = half ? (cQT - 1 - pidx) : pidx;  // pair (p, 15-p): 17 k-tiles
#pragma unroll
    for (int ch = 0; ch < 8; ++ch) {
      int idx = tid + ch * 256;
      int r = idx >> 5, cb = idx & 31;
      float4 qv = *(const float4*)(qhbase + (size_t)(qt * 64 + r) * cDq + cb * 4);
      qv.x *= cSCALE; qv.y *= cSCALE; qv.z *= cSCALE; qv.w *= cSCALE;
      *(float4*)&Qs[swzKQ(r, cb)] = qv;
    }
    float4 kreg[8];
#pragma unroll
    for (int ch = 0; ch < 8; ++ch) {
      int idx = tid + ch * 256;
      int r = idx >> 5, cb = idx & 31;
      kreg[ch] = *(const float4*)(kbase + (size_t)r * cDkv + cb * 4);
    }
    float m[4], l[4], O[4][8];
#pragma unroll
    for (int i = 0; i < 4; ++i) {
      m[i] = -1e30f;
      l[i] = 0.f;
#pragma unroll
      for (int j = 0; j < 8; ++j) O[i][j] = 0.f;
    }
    __syncthreads();

    for (int kt = 0; kt <= qt; ++kt) {
#pragma unroll
      for (int ch = 0; ch < 8; ++ch) {
        int idx = tid + ch * 256;
        *(float4*)&KVs[swzKQ(idx >> 5, idx & 31)] = kreg[ch];
      }
      __syncthreads();
      float4 vreg[8];
#pragma unroll
      for (int ch = 0; ch < 8; ++ch) {
        int idx = tid + ch * 256;
        int r = idx >> 5, cb = idx & 31;
        vreg[ch] = *(const float4*)(vbase + (size_t)(kt * 64 + r) * cDkv + cb * 4);
      }
      float acc[4][4] = {};
#pragma unroll 8
      for (int dblk = 0; dblk < 32; ++dblk) {
        float4 a4[4], b4[4];
#pragma unroll
        for (int i = 0; i < 4; ++i)
          a4[i] = *(const float4*)&Qs[swzKQ(ty * 4 + i, dblk)];
#pragma unroll
        for (int j = 0; j < 4; ++j)
          b4[j] = *(const float4*)&KVs[swzKQ(tx * 4 + j, dblk)];
#pragma unroll
        for (int i = 0; i < 4; ++i)
#pragma unroll
          for (int j = 0; j < 4; ++j)
            acc[i][j] += a4[i].x * b4[j].x + a4[i].y * b4[j].y +
                         a4[i].z * b4[j].z + a4[i].w * b4[j].w;
      }
      if (kt == qt) {
#pragma unroll
        for (int i = 0; i < 4; ++i)
#pragma unroll
          for (int j = 0; j < 4; ++j)
            if (tx * 4 + j > ty * 4 + i) acc[i][j] = -1e30f;
      }
      float ps[4][4];
#pragma unroll
      for (int i = 0; i < 4; ++i) {
        float rm = fmaxf(fmaxf(acc[i][0], acc[i][1]), fmaxf(acc[i][2], acc[i][3]));
#pragma unroll
        for (int msk = 1; msk < 16; msk <<= 1) rm = fmaxf(rm, __shfl_xor(rm, msk));
        float nm = fmaxf(m[i], rm);
        float sc_ = __expf(m[i] - nm);
        float rs = 0.f;
#pragma unroll
        for (int j = 0; j < 4; ++j) {
          ps[i][j] = __expf(acc[i][j] - nm);
          rs += ps[i][j];
        }
#pragma unroll
        for (int msk = 1; msk < 16; msk <<= 1) rs += __shfl_xor(rs, msk);
        l[i] = l[i] * sc_ + rs;
        m[i] = nm;
#pragma unroll
        for (int j = 0; j < 8; ++j) O[i][j] *= sc_;
      }
      __syncthreads();
#pragma unroll
      for (int ch = 0; ch < 8; ++ch) {
        int idx = tid + ch * 256;
        *(float4*)&KVs[swzKQ(idx >> 5, idx & 31)] = vreg[ch];
      }
      __syncthreads();
      if (kt < qt) {
#pragma unroll
        for (int ch = 0; ch < 8; ++ch) {
          int idx = tid + ch * 256;
          int r = idx >> 5, cb = idx & 31;
          kreg[ch] =
              *(const float4*)(kbase + (size_t)((kt + 1) * 64 + r) * cDkv + cb * 4);
        }
      }
#pragma unroll
      for (int kc = 0; kc < 16; ++kc) {
        float4 va[4], vb[4];
#pragma unroll
        for (int q = 0; q < 4; ++q) {
          int kk = kc * 4 + q;
          va[q] = *(const float4*)&KVs[swzKQ(kk, tx)];
          vb[q] = *(const float4*)&KVs[swzKQ(kk, tx + 16)];
        }
        int src = (tid & 48) | kc;
#pragma unroll
        for (int q = 0; q < 4; ++q)
#pragma unroll
          for (int i = 0; i < 4; ++i) {
            float pq = __shfl(ps[i][q], src);
            O[i][0] += pq * va[q].x;
            O[i][1] += pq * va[q].y;
            O[i][2] += pq * va[q].z;
            O[i][3] += pq * va[q].w;
            O[i][4] += pq * vb[q].x;
            O[i][5] += pq * vb[q].y;
            O[i][6] += pq * vb[q].z;
            O[i][7] += pq * vb[q].w;
          }
      }
      __syncthreads();
    }  // kt
#pragma unroll
    for (int i = 0; i < 4; ++i) {
      float inv = 1.f / l[i];
      float* orow = qhbase + (size_t)(qt * 64 + ty * 4 + i) * cDq;
      *(float4*)(orow + tx * 4) =
          make_float4(O[i][0] * inv, O[i][1] * inv, O[i][2] * inv, O[i][3] * inv);
      *(float4*)(orow + 64 + tx * 4) =
          make_float4(O[i][4] * inv, O[i][5] * inv, O[i][6] * inv, O[i][7] * inv);
    }
  }  // half
}

// ---------------- router: logits, top-2, compaction ------------------------
__global__ void k_zero_counts(int* __restrict__ counts) {
  if (threadIdx.x < cE) counts[threadIdx.x] = 0;
}

__global__ __launch_bounds__(64) void k_route(
    const float* __restrict__ x2, const float* __restrict__ gw,
    float* __restrict__ topw, int* __restrict__ counts, int* __restrict__ lists) {
  int t = blockIdx.x, lane = threadIdx.x;
  float acc[cE];
#pragma unroll
  for (int e = 0; e < cE; ++e) acc[e] = 0.f;
  const float* xr = x2 + (size_t)t * cH;
  for (int hh = lane; hh < cH; hh += 64) {
    float xv = xr[hh];
#pragma unroll
    for (int e = 0; e < cE; ++e) acc[e] += xv * gw[e * cH + hh];
  }
#pragma unroll
  for (int e = 0; e < cE; ++e)
    for (int off = 32; off > 0; off >>= 1) acc[e] += __shfl_down(acc[e], off);
  if (lane == 0) {
    int i0 = 0;
    float l0 = acc[0];
#pragma unroll
    for (int e = 1; e < cE; ++e)
      if (acc[e] > l0) { l0 = acc[e]; i0 = e; }
    int i1 = -1;
    float l1 = -1e30f;
#pragma unroll
    for (int e = 0; e < cE; ++e)
      if (e != i0 && acc[e] > l1) { l1 = acc[e]; i1 = e; }
    if (i1 < 0) { i1 = (i0 + 1) & 7; l1 = l0; }  // NaN-safe
    float r = expf(l1 - l0);  // top-2 softmax renorm == sigmoid of gap
    topw[t * 2 + 0] = 1.f / (1.f + r);
    topw[t * 2 + 1] = r / (1.f + r);
    int p0 = atomicAdd(&counts[i0], 1);
    lists[i0 * cT + p0] = t * 2;      // entry = token*2 + slot
    int p1 = atomicAdd(&counts[i1], 1);
    lists[i1 * cT + p1] = t * 2 + 1;
  }
}

// ------- fused MoE gate+up MFMA GEMM + SiLU*up*route-weight -> act ---------
// 128x128 tile, BK=32, 4 waves, 4x4 16x16x32 bf16 frags/wave, fp32 acc.
__global__ __launch_bounds__(256, 2) void k_mfma_gateup(
    const float* __restrict__ X, const float* __restrict__ Wg,
    const float* __restrict__ Wu, const int* __restrict__ counts,
    const int* __restrict__ lists, const float* __restrict__ topw,
    float* __restrict__ act) {
  int e = blockIdx.z;
  int cnt = counts[e];
  int mBase = blockIdx.y * 128;
  if (mBase >= cnt) return;
  int nBase = blockIdx.x * 128;
  __shared__ __align__(16) short As[128 * 32];
  __shared__ __align__(16) short Gs[128 * 32];
  __shared__ __align__(16) short Us[128 * 32];
  __shared__ int rowE[128];
  int tid = threadIdx.x;
  if (tid < 128) {
    int r = mBase + tid;
    rowE[tid] = (r < cnt) ? lists[e * cT + r] : -1;
  }
  __syncthreads();
  const float* gbase = Wg + (size_t)e * cI * cH;
  const float* ubase = Wu + (size_t)e * cI * cH;
  int sdst[2];
  const float* aptr[2];
  const float* gptr[2];
  const float* uptr[2];
#pragma unroll
  for (int b2 = 0; b2 < 2; ++b2) {
    int bid = tid + b2 * 256;
    int row = bid >> 2, blk = bid & 3;
    sdst[b2] = row * 4 + (blk ^ ((row >> 1) & 3));
    int ent = rowE[row];
    int arow = (ent < 0) ? 0 : (ent >> 1);
    aptr[b2] = X + (size_t)arow * cH + blk * 8;
    gptr[b2] = gbase + (size_t)(nBase + row) * cH + blk * 8;
    uptr[b2] = ubase + (size_t)(nBase + row) * cH + blk * 8;
  }
  int w = tid >> 6, l = tid & 63;
  int wr = (w >> 1) * 64, wc = (w & 1) * 64;
  int sub = l >> 4, l16 = l & 15;
  int offA[4], offB[4];
#pragma unroll
  for (int i = 0; i < 4; ++i) {
    int ra = wr + i * 16 + l16;
    offA[i] = ra * 4 + (sub ^ ((ra >> 1) & 3));
    int rb = wc + i * 16 + l16;
    offB[i] = rb * 4 + (sub ^ ((rb >> 1) & 3));
  }
  f32x4 accg[4][4] = {}, accu[4][4] = {};
  uint4* As4 = (uint4*)As;
  uint4* Gs4 = (uint4*)Gs;
  uint4* Us4 = (uint4*)Us;
  const bf16x8* Af = (const bf16x8*)As;
  const bf16x8* Gf = (const bf16x8*)Gs;
  const bf16x8* Uf = (const bf16x8*)Us;
  for (int k0 = 0; k0 < cH; k0 += 32) {
    float4 av0[2], av1[2], gv0[2], gv1[2], uv0[2], uv1[2];
#pragma unroll
    for (int b2 = 0; b2 < 2; ++b2) {
      av0[b2] = *(const float4*)(aptr[b2] + k0);
      av1[b2] = *(const float4*)(aptr[b2] + k0 + 4);
      gv0[b2] = *(const float4*)(gptr[b2] + k0);
      gv1[b2] = *(const float4*)(gptr[b2] + k0 + 4);
      uv0[b2] = *(const float4*)(uptr[b2] + k0);
      uv1[b2] = *(const float4*)(uptr[b2] + k0 + 4);
    }
    __syncthreads();  // previous iteration's frag reads done
#pragma unroll
    for (int b2 = 0; b2 < 2; ++b2) {
      As4[sdst[b2]] = pack8(av0[b2], av1[b2]);
      Gs4[sdst[b2]] = pack8(gv0[b2], gv1[b2]);
      Us4[sdst[b2]] = pack8(uv0[b2], uv1[b2]);
    }
    __syncthreads();  // staged tile visible
    bf16x8 af[4];
#pragma unroll
    for (int i = 0; i < 4; ++i) af[i] = Af[offA[i]];
#pragma unroll
    for (int j = 0; j < 4; ++j) {
      bf16x8 bg = Gf[offB[j]];
      bf16x8 bu = Uf[offB[j]];
#pragma unroll
      for (int i = 0; i < 4; ++i) {
        accg[i][j] = __builtin_amdgcn_mfma_f32_16x16x32_bf16(
            af[i], bg, accg[i][j], 0, 0, 0);
        accu[i][j] = __builtin_amdgcn_mfma_f32_16x16x32_bf16(
            af[i], bu, accu[i][j], 0, 0, 0);
      }
    }
  }
  // C/D layout (verified): col = lane&15, row = (lane>>4)*4 + reg
#pragma unroll
  for (int i = 0; i < 4; ++i) {
#pragma unroll
    for (int rr = 0; rr < 4; ++rr) {
      int lr = wr + i * 16 + sub * 4 + rr;
      int ent = rowE[lr];
      if (ent < 0) continue;
      float wgt = topw[ent];
#pragma unroll
      for (int j = 0; j < 4; ++j) {
        int n = nBase + wc + j * 16 + l16;
        float g = accg[i][j][rr], u = accu[i][j][rr];
        float sg = g / (1.f + __expf(-g));
        act[(size_t)ent * cI + n] = sg * u * wgt;
      }
    }
  }
}

// ------- MoE down MFMA GEMM, gather act rows, atomicAdd into F -------------
__global__ __launch_bounds__(256, 2) void k_mfma_down(
    const float* __restrict__ act, const float* __restrict__ Wd,
    const int* __restrict__ counts, const int* __restrict__ lists,
    float* __restrict__ F) {
  int e = blockIdx.z;
  int cnt = counts[e];
  int mBase = blockIdx.y * 128;
  if (mBase >= cnt) return;
  int nBase = blockIdx.x * 128;
  __shared__ __align__(16) short As[128 * 32];
  __shared__ __align__(16) short Bs[128 * 32];
  __shared__ int rowE[128];
  int tid = threadIdx.x;
  if (tid < 128) {
    int r = mBase + tid;
    rowE[tid] = (r < cnt) ? lists[e * cT + r] : -1;
  }
  __syncthreads();
  const float* wbase = Wd + (size_t)e * cH * cI;
  int sdst[2];
  const float* aptr[2];
  const float* wptr[2];
#pragma unroll
  for (int b2 = 0; b2 < 2; ++b2) {
    int bid = tid + b2 * 256;
    int row = bid >> 2, blk = bid & 3;
    sdst[b2] = row * 4 + (blk ^ ((row >> 1) & 3));
    int ent = rowE[row];
    int arow = (ent < 0) ? 0 : ent;
    aptr[b2] = act + (size_t)arow * cI + blk * 8;
    wptr[b2] = wbase + (size_t)(nBase + row) * cI + blk * 8;
  }
  int w = tid >> 6, l = tid & 63;
  int wr = (w >> 1) * 64, wc = (w & 1) * 64;
  int sub = l >> 4, l16 = l & 15;
  int offA[4], offB[4];
#pragma unroll
  for (int i = 0; i < 4; ++i) {
    int ra = wr + i * 16 + l16;
    offA[i] = ra * 4 + (sub ^ ((ra >> 1) & 3));
    int rb = wc + i * 16 + l16;
    offB[i] = rb * 4 + (sub ^ ((rb >> 1) & 3));
  }
  f32x4 acc[4][4] = {};
  uint4* As4 = (uint4*)As;
  uint4* Bs4 = (uint4*)Bs;
  const bf16x8* Af = (const bf16x8*)As;
  const bf16x8* Bf = (const bf16x8*)Bs;
  for (int k0 = 0; k0 < cI; k0 += 32) {
    float4 av0[2], av1[2], wv0[2], wv1[2];
#pragma unroll
    for (int b2 = 0; b2 < 2; ++b2) {
      av0[b2] = *(const float4*)(aptr[b2] + k0);
      av1[b2] = *(const float4*)(aptr[b2] + k0 + 4);
      wv0[b2] = *(const float4*)(wptr[b2] + k0);
      wv1[b2] = *(const float4*)(wptr[b2] + k0 + 4);
    }
    __syncthreads();
#pragma unroll
    for (int b2 = 0; b2 < 2; ++b2) {
      As4[sdst[b2]] = pack8(av0[b2], av1[b2]);
      Bs4[sdst[b2]] = pack8(wv0[b2], wv1[b2]);
    }
    __syncthreads();
    bf16x8 af[4], bfr[4];
#pragma unroll
    for (int i = 0; i < 4; ++i) af[i] = Af[offA[i]];
#pragma unroll
    for (int j = 0; j < 4; ++j) bfr[j] = Bf[offB[j]];
#pragma unroll
    for (int i = 0; i < 4; ++i)
#pragma unroll
      for (int j = 0; j < 4; ++j)
        acc[i][j] = __builtin_amdgcn_mfma_f32_16x16x32_bf16(
            af[i], bfr[j], acc[i][j], 0, 0, 0);
  }
#pragma unroll
  for (int i = 0; i < 4; ++i) {
#pragma unroll
    for (int rr = 0; rr < 4; ++rr) {
      int lr = wr + i * 16 + sub * 4 + rr;
      int ent = rowE[lr];
      if (ent < 0) continue;
      int t = ent >> 1;
#pragma unroll
      for (int j = 0; j < 4; ++j) {
        int n = nBase + wc + j * 16 + l16;
        atomicAdd(&F[(size_t)t * cH + n], acc[i][j][rr]);
      }
    }
  }
}

}  // namespace

extern "C" void kernel_launch(void* const* d_in, const int* in_sizes, int n_in,
                              void* d_out, int out_size, void* d_ws, size_t ws_size,
                              hipStream_t stream) {
  (void)n_in; (void)out_size; (void)ws_size;
  int off = (in_sizes[1] == 1) ? 0 : -1;
  const float* hidden   = (const float*)d_in[0];
  const float* cosb     = (const float*)d_in[2 + off];
  const float* sinb     = (const float*)d_in[3 + off];
  const float* w_q      = (const float*)d_in[5 + off];
  const float* w_k      = (const float*)d_in[6 + off];
  const float* w_v      = (const float*)d_in[7 + off];
  const float* w_o      = (const float*)d_in[8 + off];
  const float* q_norm_w = (const float*)d_in[9 + off];
  const float* k_norm_w = (const float*)d_in[10 + off];
  const float* ln1_w    = (const float*)d_in[11 + off];
  const float* ln2_w    = (const float*)d_in[12 + off];
  const float* gate_w   = (const float*)d_in[13 + off];
  const float* w_gate_e = (const float*)d_in[14 + off];
  const float* w_up_e   = (const float*)d_in[15 + off];
  const float* w_down_e = (const float*)d_in[16 + off];
  float* F = (float*)d_out;             // fp32 output == residual accumulator
  int cosBS = in_sizes[2 + off] / cHD;  // 2048 if (B,S,HD)

  float* ws = (float*)d_ws;
  float* xbuf  = ws;                        // cT*cH (16MB): ln1 out -> ln2 out
  float* qcbuf = xbuf + (size_t)cT * cH;    // cT*cDq (16MB): q -> ctx -> act
  float* kbuf  = qcbuf + (size_t)cT * cDq;  // cT*cDkv (4MB)
  float* vbuf  = kbuf + (size_t)cT * cDkv;  // cT*cDkv (4MB)
  float* topw  = vbuf + (size_t)cT * cDkv;  // cT*2
  int* counts  = (int*)(topw + (size_t)cT * 2);
  int* lists   = counts + cE;               // cE*cT
  float* act   = qcbuf;                     // reuse after O-proj consumed ctx

  k_rmsnorm<<<cT, 256, 0, stream>>>(hidden, ln1_w, xbuf);
  k_gemm_xwT<false><<<dim3(cDq / 64, cT / 64), 256, 0, stream>>>(
      xbuf, w_q, qcbuf, nullptr, cT, cDq, cH);
  k_gemm_xwT<false><<<dim3(cDkv / 64, cT / 64), 256, 0, stream>>>(
      xbuf, w_k, kbuf, nullptr, cT, cDkv, cH);
  k_gemm_xwT<false><<<dim3(cDkv / 64, cT / 64), 256, 0, stream>>>(
      xbuf, w_v, vbuf, nullptr, cT, cDkv, cH);
  k_qknorm_rope<<<dim3(cT, cNH + cNKV), 128, 0, stream>>>(
      qcbuf, kbuf, q_norm_w, k_norm_w, cosb, sinb, cosBS);
  k_attn_tiled<<<dim3(cQT / 2, cNH, cB), 256, 0, stream>>>(qcbuf, kbuf, vbuf);
  k_gemm_xwT<true><<<dim3(cH / 64, cT / 64), 256, 0, stream>>>(
      qcbuf, w_o, F, hidden, cT, cH, cH);
  k_rmsnorm<<<cT, 256, 0, stream>>>(F, ln2_w, xbuf);
  k_zero_counts<<<1, 64, 0, stream>>>(counts);
  k_route<<<cT, 64, 0, stream>>>(xbuf, gate_w, topw, counts, lists);
  k_mfma_gateup<<<dim3(cI / 128, cT / 128, cE), 256, 0, stream>>>(
      xbuf, w_gate_e, w_up_e, counts, lists, topw, act);
  k_mfma_down<<<dim3(cH / 128, cT / 128, cE), 256, 0, stream>>>(
      act, w_down_e, counts, lists, F);
}

// Round 5
// 1010.957 us; speedup vs baseline: 2.9733x; 1.4859x over previous
//
#include <hip/hip_runtime.h>

// Qwen3 MoE decoder layer, MI355X. Round 10: dense QKV/O GEMMs (≈1000 us of
// fp32 VALU at 42 TF) moved to split-bf16 3-pass MFMA: per operand,
// hi=trunc_bf16(x), lo=bf16(x-hi) (exact), acc += ah*bh + al*bh + ah*bl.
// Error ~2^-16 relative -> router logit noise ~2e-5 (no top-2 flips; R8's
// plain-bf16 4e-3 flipped ~8 tokens). QKV fused in one kernel (384 blocks).
// Attention, rmsnorm, rope, router, MoE MFMA (plain bf16, post-routing)
// unchanged from the PASSING 1502-us R9.

namespace {

constexpr int cB = 2, cS = 1024, cH = 2048;
constexpr int cNH = 16, cNKV = 4, cHD = 128;
constexpr int cE = 8, cI = 768;
constexpr int cT = cB * cS;        // 2048 tokens
constexpr int cDq = cNH * cHD;     // 2048
constexpr int cDkv = cNKV * cHD;   // 512
constexpr float cEPS = 1e-6f;
constexpr float cSCALE = 0.08838834764831845f;  // HD^-0.5
constexpr int cQT = cS / 64;       // 16 q-tiles per (b,h)

typedef __attribute__((ext_vector_type(8))) short bf16x8;
typedef __attribute__((ext_vector_type(4))) float f32x4;

// fp32 -> bf16 round-to-nearest-even, packed pair (f0 low, f1 high)
__device__ __forceinline__ unsigned pack2(float f0, float f1) {
  unsigned u0 = __float_as_uint(f0), u1 = __float_as_uint(f1);
  unsigned r0 = (u0 + (0x7FFFu + ((u0 >> 16) & 1u))) >> 16;
  unsigned r1 = (u1 + (0x7FFFu + ((u1 >> 16) & 1u))) & 0xFFFF0000u;
  return r0 | r1;
}
__device__ __forceinline__ uint4 pack8(const float4& a, const float4& b) {
  return make_uint4(pack2(a.x, a.y), pack2(a.z, a.w),
                    pack2(b.x, b.y), pack2(b.z, b.w));
}

// truncating split helpers (Dekker-style two-term bf16 decomposition)
__device__ __forceinline__ unsigned pack2t(float f0, float f1) {
  return (__float_as_uint(f0) >> 16) | (__float_as_uint(f1) & 0xFFFF0000u);
}
__device__ __forceinline__ float hi_of(float f) {
  return __uint_as_float(__float_as_uint(f) & 0xFFFF0000u);
}
__device__ __forceinline__ void split8(const float4& x, const float4& y,
                                       uint4& h, uint4& l) {
  h = make_uint4(pack2t(x.x, x.y), pack2t(x.z, x.w),
                 pack2t(y.x, y.y), pack2t(y.z, y.w));
  float l0 = x.x - hi_of(x.x), l1 = x.y - hi_of(x.y);
  float l2 = x.z - hi_of(x.z), l3 = x.w - hi_of(x.w);
  float l4 = y.x - hi_of(y.x), l5 = y.y - hi_of(y.y);
  float l6 = y.z - hi_of(y.z), l7 = y.w - hi_of(y.w);
  l = make_uint4(pack2t(l0, l1), pack2t(l2, l3), pack2t(l4, l5), pack2t(l6, l7));
}

// ---------------- RMSNorm (fp32) ----------------
__global__ __launch_bounds__(256) void k_rmsnorm(
    const float* __restrict__ xin, const float* __restrict__ w,
    float* __restrict__ y) {
  int t = blockIdx.x, tid = threadIdx.x;
  __shared__ float red[256];
  const float* xr = xin + (size_t)t * cH;
  float xv[8];
  float ss = 0.f;
#pragma unroll
  for (int i = 0; i < 8; ++i) {
    xv[i] = xr[tid + i * 256];
    ss += xv[i] * xv[i];
  }
  red[tid] = ss;
  __syncthreads();
  for (int s = 128; s > 0; s >>= 1) {
    if (tid < s) red[tid] += red[tid + s];
    __syncthreads();
  }
  float inv = rsqrtf(red[0] / (float)cH + cEPS);
#pragma unroll
  for (int i = 0; i < 8; ++i)
    y[(size_t)t * cH + tid + i * 256] = xv[i] * inv * w[tid + i * 256];
}

// ---- split-bf16 3-pass MFMA GEMM core (128x128 tile, BK=32, 256 thr) ------
// C[m,n] = sum_k A[m,k]*W[n,k], error ~2^-16 relative (routing-safe).
// Shared geometry with the proven R9 MFMA template.
#define SGEMM_BODY(APTR_EXPR, WPTR_EXPR, KDIM, EPILOGUE)                      \
  __shared__ __align__(16) short Ah[128 * 32];                                \
  __shared__ __align__(16) short Al[128 * 32];                                \
  __shared__ __align__(16) short Bh[128 * 32];                                \
  __shared__ __align__(16) short Bl[128 * 32];                                \
  int tid = threadIdx.x;                                                      \
  int sdst[2];                                                                \
  const float* aptr[2];                                                       \
  const float* wptr[2];                                                       \
  _Pragma("unroll") for (int b2 = 0; b2 < 2; ++b2) {                          \
    int bid = tid + b2 * 256;                                                 \
    int row = bid >> 2, blk = bid & 3;                                        \
    sdst[b2] = row * 4 + (blk ^ ((row >> 1) & 3));                            \
    aptr[b2] = (APTR_EXPR) + blk * 8;                                         \
    wptr[b2] = (WPTR_EXPR) + blk * 8;                                         \
  }                                                                           \
  int w = tid >> 6, l = tid & 63;                                             \
  int wr = (w >> 1) * 64, wc = (w & 1) * 64;                                  \
  int sub = l >> 4, l16 = l & 15;                                             \
  int offA[4], offB[4];                                                       \
  _Pragma("unroll") for (int i = 0; i < 4; ++i) {                             \
    int ra = wr + i * 16 + l16;                                               \
    offA[i] = ra * 4 + (sub ^ ((ra >> 1) & 3));                               \
    int rb = wc + i * 16 + l16;                                               \
    offB[i] = rb * 4 + (sub ^ ((rb >> 1) & 3));                               \
  }                                                                           \
  f32x4 acc[4][4] = {};                                                       \
  uint4* Ah4 = (uint4*)Ah;                                                    \
  uint4* Al4 = (uint4*)Al;                                                    \
  uint4* Bh4 = (uint4*)Bh;                                                    \
  uint4* Bl4 = (uint4*)Bl;                                                    \
  const bf16x8* Ahf = (const bf16x8*)Ah;                                      \
  const bf16x8* Alf = (const bf16x8*)Al;                                      \
  const bf16x8* Bhf = (const bf16x8*)Bh;                                      \
  const bf16x8* Blf = (const bf16x8*)Bl;                                      \
  for (int k0 = 0; k0 < (KDIM); k0 += 32) {                                   \
    float4 av0[2], av1[2], wv0[2], wv1[2];                                    \
    _Pragma("unroll") for (int b2 = 0; b2 < 2; ++b2) {                        \
      av0[b2] = *(const float4*)(aptr[b2] + k0);                              \
      av1[b2] = *(const float4*)(aptr[b2] + k0 + 4);                          \
      wv0[b2] = *(const float4*)(wptr[b2] + k0);                              \
      wv1[b2] = *(const float4*)(wptr[b2] + k0 + 4);                          \
    }                                                                         \
    __syncthreads();                                                          \
    _Pragma("unroll") for (int b2 = 0; b2 < 2; ++b2) {                        \
      uint4 h, lo;                                                            \
      split8(av0[b2], av1[b2], h, lo);                                        \
      Ah4[sdst[b2]] = h;                                                      \
      Al4[sdst[b2]] = lo;                                                     \
      split8(wv0[b2], wv1[b2], h, lo);                                        \
      Bh4[sdst[b2]] = h;                                                      \
      Bl4[sdst[b2]] = lo;                                                     \
    }                                                                         \
    __syncthreads();                                                          \
    bf16x8 ah[4], al[4], bh[4], bl[4];                                        \
    _Pragma("unroll") for (int i = 0; i < 4; ++i) {                           \
      ah[i] = Ahf[offA[i]];                                                   \
      al[i] = Alf[offA[i]];                                                   \
    }                                                                         \
    _Pragma("unroll") for (int j = 0; j < 4; ++j) {                           \
      bh[j] = Bhf[offB[j]];                                                   \
      bl[j] = Blf[offB[j]];                                                   \
    }                                                                         \
    _Pragma("unroll") for (int i = 0; i < 4; ++i)                             \
        _Pragma("unroll") for (int j = 0; j < 4; ++j) {                       \
      acc[i][j] = __builtin_amdgcn_mfma_f32_16x16x32_bf16(ah[i], bh[j],       \
                                                          acc[i][j], 0, 0, 0);\
      acc[i][j] = __builtin_amdgcn_mfma_f32_16x16x32_bf16(al[i], bh[j],       \
                                                          acc[i][j], 0, 0, 0);\
      acc[i][j] = __builtin_amdgcn_mfma_f32_16x16x32_bf16(ah[i], bl[j],       \
                                                          acc[i][j], 0, 0, 0);\
    }                                                                         \
  }                                                                           \
  _Pragma("unroll") for (int i = 0; i < 4; ++i) {                             \
    _Pragma("unroll") for (int rr = 0; rr < 4; ++rr) {                        \
      int lr = wr + i * 16 + sub * 4 + rr;                                    \
      _Pragma("unroll") for (int j = 0; j < 4; ++j) {                         \
        int nn = wc + j * 16 + l16;                                           \
        float vv = acc[i][j][rr];                                             \
        EPILOGUE;                                                             \
      }                                                                       \
    }                                                                         \
  }

// Fused QKV: A = ln1(x); n-tiles 0..15 -> q, 16..19 -> k, 20..23 -> v.
__global__ __launch_bounds__(256, 2) void k_sgemm_qkv(
    const float* __restrict__ A, const float* __restrict__ Wq,
    const float* __restrict__ Wk, const float* __restrict__ Wv,
    float* __restrict__ Cq, float* __restrict__ Ck, float* __restrict__ Cv) {
  int nBase = blockIdx.x * 128;
  int mBase = blockIdx.y * 128;
  const float* W;
  float* C;
  int Nout, ncol;
  if (nBase < cDq) {
    W = Wq; C = Cq; Nout = cDq; ncol = nBase;
  } else if (nBase < cDq + cDkv) {
    W = Wk; C = Ck; Nout = cDkv; ncol = nBase - cDq;
  } else {
    W = Wv; C = Cv; Nout = cDkv; ncol = nBase - cDq - cDkv;
  }
  SGEMM_BODY(A + (size_t)(mBase + row) * cH,
             W + (size_t)(ncol + row) * cH, cH,
             C[(size_t)(mBase + lr) * Nout + ncol + nn] = vv)
}

// O-projection + residual: F = ctx @ w_o^T + hidden
__global__ __launch_bounds__(256, 2) void k_sgemm_o(
    const float* __restrict__ A, const float* __restrict__ W,
    float* __restrict__ C, const float* __restrict__ resid) {
  int nBase = blockIdx.x * 128;
  int mBase = blockIdx.y * 128;
  SGEMM_BODY(A + (size_t)(mBase + row) * cH,
             W + (size_t)(nBase + row) * cH, cH,
             {
               size_t idx = (size_t)(mBase + lr) * cH + nBase + nn;
               C[idx] = vv + resid[idx];
             })
}

// ---------------- per-head RMSNorm + RoPE on q and k (in place) ------------
__global__ __launch_bounds__(128) void k_qknorm_rope(
    float* qbuf, float* kbuf,
    const float* __restrict__ qw, const float* __restrict__ kw,
    const float* __restrict__ cosb, const float* __restrict__ sinb,
    int cosBS) {
  int t = blockIdx.x, head = blockIdx.y, d = threadIdx.x;
  float* buf;
  const float* w;
  if (head < cNH) {
    buf = qbuf + (size_t)t * cDq + head * cHD;
    w = qw;
  } else {
    buf = kbuf + (size_t)t * cDkv + (head - cNH) * cHD;
    w = kw;
  }
  __shared__ float xs[cHD];
  __shared__ float red[cHD];
  float x = buf[d];
  xs[d] = x;
  red[d] = x * x;
  __syncthreads();
  for (int s = 64; s > 0; s >>= 1) {
    if (d < s) red[d] += red[d + s];
    __syncthreads();
  }
  float inv = rsqrtf(red[0] / (float)cHD + cEPS);
  int od = d ^ 64;  // rotate_half partner
  float y = x * inv * w[d];
  float yo = xs[od] * inv * w[od];
  float rot = (d < 64) ? -yo : yo;
  size_t ci = (size_t)(t % cosBS) * cHD + d;
  buf[d] = y * cosb[ci] + rot * sinb[ci];
}

// ---------------- tiled causal attention (fp32, online softmax) ------------
__device__ __forceinline__ int swzKQ(int r, int cb) {  // cb: float4 block 0..31
  return r * 128 + ((cb ^ ((r >> 2) & 7)) << 2);
}

__global__ __launch_bounds__(256) void k_attn_tiled(
    float* qc, const float* __restrict__ k, const float* __restrict__ v) {
  __shared__ __align__(16) float Qs[64 * 128];   // 32 KB
  __shared__ __align__(16) float KVs[64 * 128];  // 32 KB, K then V per tile
  int pidx = blockIdx.x, h = blockIdx.y, b = blockIdx.z;
  int kvh = h >> 2;  // rep = NH/NKV = 4
  int tid = threadIdx.x;
  int tx = tid & 15, ty = tid >> 4;
  const float* kbase = k + (size_t)b * cS * cDkv + kvh * cHD;
  const float* vbase = v + (size_t)b * cS * cDkv + kvh * cHD;
  float* qhbase = qc + (size_t)b * cS * cDq + h * cHD;

  for (int half = 0; half < 2; ++half) {
    int qt = half ? (cQT - 1 - pidx) : pidx;  // pair (p, 15-p): 17 k-tiles
#pragma unroll
    for (int ch = 0; ch < 8; ++ch) {
      int idx = tid + ch * 256;
      int r = idx >> 5, cb = idx & 31;
      float4 qv = *(const float4*)(qhbase + (size_t)(qt * 64 + r) * cDq + cb * 4);
      qv.x *= cSCALE; qv.y *= cSCALE; qv.z *= cSCALE; qv.w *= cSCALE;
      *(float4*)&Qs[swzKQ(r, cb)] = qv;
    }
    float4 kreg[8];
#pragma unroll
    for (int ch = 0; ch < 8; ++ch) {
      int idx = tid + ch * 256;
      int r = idx >> 5, cb = idx & 31;
      kreg[ch] = *(const float4*)(kbase + (size_t)r * cDkv + cb * 4);
    }
    float m[4], l[4], O[4][8];
#pragma unroll
    for (int i = 0; i < 4; ++i) {
      m[i] = -1e30f;
      l[i] = 0.f;
#pragma unroll
      for (int j = 0; j < 8; ++j) O[i][j] = 0.f;
    }
    __syncthreads();

    for (int kt = 0; kt <= qt; ++kt) {
#pragma unroll
      for (int ch = 0; ch < 8; ++ch) {
        int idx = tid + ch * 256;
        *(float4*)&KVs[swzKQ(idx >> 5, idx & 31)] = kreg[ch];
      }
      __syncthreads();
      float4 vreg[8];
#pragma unroll
      for (int ch = 0; ch < 8; ++ch) {
        int idx = tid + ch * 256;
        int r = idx >> 5, cb = idx & 31;
        vreg[ch] = *(const float4*)(vbase + (size_t)(kt * 64 + r) * cDkv + cb * 4);
      }
      float acc[4][4] = {};
#pragma unroll 8
      for (int dblk = 0; dblk < 32; ++dblk) {
        float4 a4[4], b4[4];
#pragma unroll
        for (int i = 0; i < 4; ++i)
          a4[i] = *(const float4*)&Qs[swzKQ(ty * 4 + i, dblk)];
#pragma unroll
        for (int j = 0; j < 4; ++j)
          b4[j] = *(const float4*)&KVs[swzKQ(tx * 4 + j, dblk)];
#pragma unroll
        for (int i = 0; i < 4; ++i)
#pragma unroll
          for (int j = 0; j < 4; ++j)
            acc[i][j] += a4[i].x * b4[j].x + a4[i].y * b4[j].y +
                         a4[i].z * b4[j].z + a4[i].w * b4[j].w;
      }
      if (kt == qt) {
#pragma unroll
        for (int i = 0; i < 4; ++i)
#pragma unroll
          for (int j = 0; j < 4; ++j)
            if (tx * 4 + j > ty * 4 + i) acc[i][j] = -1e30f;
      }
      float ps[4][4];
#pragma unroll
      for (int i = 0; i < 4; ++i) {
        float rm = fmaxf(fmaxf(acc[i][0], acc[i][1]), fmaxf(acc[i][2], acc[i][3]));
#pragma unroll
        for (int msk = 1; msk < 16; msk <<= 1) rm = fmaxf(rm, __shfl_xor(rm, msk));
        float nm = fmaxf(m[i], rm);
        float sc_ = __expf(m[i] - nm);
        float rs = 0.f;
#pragma unroll
        for (int j = 0; j < 4; ++j) {
          ps[i][j] = __expf(acc[i][j] - nm);
          rs += ps[i][j];
        }
#pragma unroll
        for (int msk = 1; msk < 16; msk <<= 1) rs += __shfl_xor(rs, msk);
        l[i] = l[i] * sc_ + rs;
        m[i] = nm;
#pragma unroll
        for (int j = 0; j < 8; ++j) O[i][j] *= sc_;
      }
      __syncthreads();
#pragma unroll
      for (int ch = 0; ch < 8; ++ch) {
        int idx = tid + ch * 256;
        *(float4*)&KVs[swzKQ(idx >> 5, idx & 31)] = vreg[ch];
      }
      __syncthreads();
      if (kt < qt) {
#pragma unroll
        for (int ch = 0; ch < 8; ++ch) {
          int idx = tid + ch * 256;
          int r = idx >> 5, cb = idx & 31;
          kreg[ch] =
              *(const float4*)(kbase + (size_t)((kt + 1) * 64 + r) * cDkv + cb * 4);
        }
      }
#pragma unroll
      for (int kc = 0; kc < 16; ++kc) {
        float4 va[4], vb[4];
#pragma unroll
        for (int q = 0; q < 4; ++q) {
          int kk = kc * 4 + q;
          va[q] = *(const float4*)&KVs[swzKQ(kk, tx)];
          vb[q] = *(const float4*)&KVs[swzKQ(kk, tx + 16)];
        }
        int src = (tid & 48) | kc;
#pragma unroll
        for (int q = 0; q < 4; ++q)
#pragma unroll
          for (int i = 0; i < 4; ++i) {
            float pq = __shfl(ps[i][q], src);
            O[i][0] += pq * va[q].x;
            O[i][1] += pq * va[q].y;
            O[i][2] += pq * va[q].z;
            O[i][3] += pq * va[q].w;
            O[i][4] += pq * vb[q].x;
            O[i][5] += pq * vb[q].y;
            O[i][6] += pq * vb[q].z;
            O[i][7] += pq * vb[q].w;
          }
      }
      __syncthreads();
    }  // kt
#pragma unroll
    for (int i = 0; i < 4; ++i) {
      float inv = 1.f / l[i];
      float* orow = qhbase + (size_t)(qt * 64 + ty * 4 + i) * cDq;
      *(float4*)(orow + tx * 4) =
          make_float4(O[i][0] * inv, O[i][1] * inv, O[i][2] * inv, O[i][3] * inv);
      *(float4*)(orow + 64 + tx * 4) =
          make_float4(O[i][4] * inv, O[i][5] * inv, O[i][6] * inv, O[i][7] * inv);
    }
  }  // half
}

// ---------------- router: logits, top-2, compaction ------------------------
__global__ void k_zero_counts(int* __restrict__ counts) {
  if (threadIdx.x < cE) counts[threadIdx.x] = 0;
}

__global__ __launch_bounds__(64) void k_route(
    const float* __restrict__ x2, const float* __restrict__ gw,
    float* __restrict__ topw, int* __restrict__ counts, int* __restrict__ lists) {
  int t = blockIdx.x, lane = threadIdx.x;
  float acc[cE];
#pragma unroll
  for (int e = 0; e < cE; ++e) acc[e] = 0.f;
  const float* xr = x2 + (size_t)t * cH;
  for (int hh = lane; hh < cH; hh += 64) {
    float xv = xr[hh];
#pragma unroll
    for (int e = 0; e < cE; ++e) acc[e] += xv * gw[e * cH + hh];
  }
#pragma unroll
  for (int e = 0; e < cE; ++e)
    for (int off = 32; off > 0; off >>= 1) acc[e] += __shfl_down(acc[e], off);
  if (lane == 0) {
    int i0 = 0;
    float l0 = acc[0];
#pragma unroll
    for (int e = 1; e < cE; ++e)
      if (acc[e] > l0) { l0 = acc[e]; i0 = e; }
    int i1 = -1;
    float l1 = -1e30f;
#pragma unroll
    for (int e = 0; e < cE; ++e)
      if (e != i0 && acc[e] > l1) { l1 = acc[e]; i1 = e; }
    if (i1 < 0) { i1 = (i0 + 1) & 7; l1 = l0; }  // NaN-safe
    float r = expf(l1 - l0);  // top-2 softmax renorm == sigmoid of gap
    topw[t * 2 + 0] = 1.f / (1.f + r);
    topw[t * 2 + 1] = r / (1.f + r);
    int p0 = atomicAdd(&counts[i0], 1);
    lists[i0 * cT + p0] = t * 2;      // entry = token*2 + slot
    int p1 = atomicAdd(&counts[i1], 1);
    lists[i1 * cT + p1] = t * 2 + 1;
  }
}

// ------- fused MoE gate+up MFMA GEMM + SiLU*up*route-weight -> act ---------
__global__ __launch_bounds__(256, 2) void k_mfma_gateup(
    const float* __restrict__ X, const float* __restrict__ Wg,
    const float* __restrict__ Wu, const int* __restrict__ counts,
    const int* __restrict__ lists, const float* __restrict__ topw,
    float* __restrict__ act) {
  int e = blockIdx.z;
  int cnt = counts[e];
  int mBase = blockIdx.y * 128;
  if (mBase >= cnt) return;
  int nBase = blockIdx.x * 128;
  __shared__ __align__(16) short As[128 * 32];
  __shared__ __align__(16) short Gs[128 * 32];
  __shared__ __align__(16) short Us[128 * 32];
  __shared__ int rowE[128];
  int tid = threadIdx.x;
  if (tid < 128) {
    int r = mBase + tid;
    rowE[tid] = (r < cnt) ? lists[e * cT + r] : -1;
  }
  __syncthreads();
  const float* gbase = Wg + (size_t)e * cI * cH;
  const float* ubase = Wu + (size_t)e * cI * cH;
  int sdst[2];
  const float* aptr[2];
  const float* gptr[2];
  const float* uptr[2];
#pragma unroll
  for (int b2 = 0; b2 < 2; ++b2) {
    int bid = tid + b2 * 256;
    int row = bid >> 2, blk = bid & 3;
    sdst[b2] = row * 4 + (blk ^ ((row >> 1) & 3));
    int ent = rowE[row];
    int arow = (ent < 0) ? 0 : (ent >> 1);
    aptr[b2] = X + (size_t)arow * cH + blk * 8;
    gptr[b2] = gbase + (size_t)(nBase + row) * cH + blk * 8;
    uptr[b2] = ubase + (size_t)(nBase + row) * cH + blk * 8;
  }
  int w = tid >> 6, l = tid & 63;
  int wr = (w >> 1) * 64, wc = (w & 1) * 64;
  int sub = l >> 4, l16 = l & 15;
  int offA[4], offB[4];
#pragma unroll
  for (int i = 0; i < 4; ++i) {
    int ra = wr + i * 16 + l16;
    offA[i] = ra * 4 + (sub ^ ((ra >> 1) & 3));
    int rb = wc + i * 16 + l16;
    offB[i] = rb * 4 + (sub ^ ((rb >> 1) & 3));
  }
  f32x4 accg[4][4] = {}, accu[4][4] = {};
  uint4* As4 = (uint4*)As;
  uint4* Gs4 = (uint4*)Gs;
  uint4* Us4 = (uint4*)Us;
  const bf16x8* Af = (const bf16x8*)As;
  const bf16x8* Gf = (const bf16x8*)Gs;
  const bf16x8* Uf = (const bf16x8*)Us;
  for (int k0 = 0; k0 < cH; k0 += 32) {
    float4 av0[2], av1[2], gv0[2], gv1[2], uv0[2], uv1[2];
#pragma unroll
    for (int b2 = 0; b2 < 2; ++b2) {
      av0[b2] = *(const float4*)(aptr[b2] + k0);
      av1[b2] = *(const float4*)(aptr[b2] + k0 + 4);
      gv0[b2] = *(const float4*)(gptr[b2] + k0);
      gv1[b2] = *(const float4*)(gptr[b2] + k0 + 4);
      uv0[b2] = *(const float4*)(uptr[b2] + k0);
      uv1[b2] = *(const float4*)(uptr[b2] + k0 + 4);
    }
    __syncthreads();  // previous iteration's frag reads done
#pragma unroll
    for (int b2 = 0; b2 < 2; ++b2) {
      As4[sdst[b2]] = pack8(av0[b2], av1[b2]);
      Gs4[sdst[b2]] = pack8(gv0[b2], gv1[b2]);
      Us4[sdst[b2]] = pack8(uv0[b2], uv1[b2]);
    }
    __syncthreads();  // staged tile visible
    bf16x8 af[4];
#pragma unroll
    for (int i = 0; i < 4; ++i) af[i] = Af[offA[i]];
#pragma unroll
    for (int j = 0; j < 4; ++j) {
      bf16x8 bg = Gf[offB[j]];
      bf16x8 bu = Uf[offB[j]];
#pragma unroll
      for (int i = 0; i < 4; ++i) {
        accg[i][j] = __builtin_amdgcn_mfma_f32_16x16x32_bf16(
            af[i], bg, accg[i][j], 0, 0, 0);
        accu[i][j] = __builtin_amdgcn_mfma_f32_16x16x32_bf16(
            af[i], bu, accu[i][j], 0, 0, 0);
      }
    }
  }
  // C/D layout (verified): col = lane&15, row = (lane>>4)*4 + reg
#pragma unroll
  for (int i = 0; i < 4; ++i) {
#pragma unroll
    for (int rr = 0; rr < 4; ++rr) {
      int lr = wr + i * 16 + sub * 4 + rr;
      int ent = rowE[lr];
      if (ent < 0) continue;
      float wgt = topw[ent];
#pragma unroll
      for (int j = 0; j < 4; ++j) {
        int n = nBase + wc + j * 16 + l16;
        float g = accg[i][j][rr], u = accu[i][j][rr];
        float sg = g / (1.f + __expf(-g));
        act[(size_t)ent * cI + n] = sg * u * wgt;
      }
    }
  }
}

// ------- MoE down MFMA GEMM, gather act rows, atomicAdd into F -------------
__global__ __launch_bounds__(256, 2) void k_mfma_down(
    const float* __restrict__ act, const float* __restrict__ Wd,
    const int* __restrict__ counts, const int* __restrict__ lists,
    float* __restrict__ F) {
  int e = blockIdx.z;
  int cnt = counts[e];
  int mBase = blockIdx.y * 128;
  if (mBase >= cnt) return;
  int nBase = blockIdx.x * 128;
  __shared__ __align__(16) short As[128 * 32];
  __shared__ __align__(16) short Bs[128 * 32];
  __shared__ int rowE[128];
  int tid = threadIdx.x;
  if (tid < 128) {
    int r = mBase + tid;
    rowE[tid] = (r < cnt) ? lists[e * cT + r] : -1;
  }
  __syncthreads();
  const float* wbase = Wd + (size_t)e * cH * cI;
  int sdst[2];
  const float* aptr[2];
  const float* wptr[2];
#pragma unroll
  for (int b2 = 0; b2 < 2; ++b2) {
    int bid = tid + b2 * 256;
    int row = bid >> 2, blk = bid & 3;
    sdst[b2] = row * 4 + (blk ^ ((row >> 1) & 3));
    int ent = rowE[row];
    int arow = (ent < 0) ? 0 : ent;
    aptr[b2] = act + (size_t)arow * cI + blk * 8;
    wptr[b2] = wbase + (size_t)(nBase + row) * cI + blk * 8;
  }
  int w = tid >> 6, l = tid & 63;
  int wr = (w >> 1) * 64, wc = (w & 1) * 64;
  int sub = l >> 4, l16 = l & 15;
  int offA[4], offB[4];
#pragma unroll
  for (int i = 0; i < 4; ++i) {
    int ra = wr + i * 16 + l16;
    offA[i] = ra * 4 + (sub ^ ((ra >> 1) & 3));
    int rb = wc + i * 16 + l16;
    offB[i] = rb * 4 + (sub ^ ((rb >> 1) & 3));
  }
  f32x4 acc[4][4] = {};
  uint4* As4 = (uint4*)As;
  uint4* Bs4 = (uint4*)Bs;
  const bf16x8* Af = (const bf16x8*)As;
  const bf16x8* Bf = (const bf16x8*)Bs;
  for (int k0 = 0; k0 < cI; k0 += 32) {
    float4 av0[2], av1[2], wv0[2], wv1[2];
#pragma unroll
    for (int b2 = 0; b2 < 2; ++b2) {
      av0[b2] = *(const float4*)(aptr[b2] + k0);
      av1[b2] = *(const float4*)(aptr[b2] + k0 + 4);
      wv0[b2] = *(const float4*)(wptr[b2] + k0);
      wv1[b2] = *(const float4*)(wptr[b2] + k0 + 4);
    }
    __syncthreads();
#pragma unroll
    for (int b2 = 0; b2 < 2; ++b2) {
      As4[sdst[b2]] = pack8(av0[b2], av1[b2]);
      Bs4[sdst[b2]] = pack8(wv0[b2], wv1[b2]);
    }
    __syncthreads();
    bf16x8 af[4], bfr[4];
#pragma unroll
    for (int i = 0; i < 4; ++i) af[i] = Af[offA[i]];
#pragma unroll
    for (int j = 0; j < 4; ++j) bfr[j] = Bf[offB[j]];
#pragma unroll
    for (int i = 0; i < 4; ++i)
#pragma unroll
      for (int j = 0; j < 4; ++j)
        acc[i][j] = __builtin_amdgcn_mfma_f32_16x16x32_bf16(
            af[i], bfr[j], acc[i][j], 0, 0, 0);
  }
#pragma unroll
  for (int i = 0; i < 4; ++i) {
#pragma unroll
    for (int rr = 0; rr < 4; ++rr) {
      int lr = wr + i * 16 + sub * 4 + rr;
      int ent = rowE[lr];
      if (ent < 0) continue;
      int t = ent >> 1;
#pragma unroll
      for (int j = 0; j < 4; ++j) {
        int n = nBase + wc + j * 16 + l16;
        atomicAdd(&F[(size_t)t * cH + n], acc[i][j][rr]);
      }
    }
  }
}

}  // namespace

extern "C" void kernel_launch(void* const* d_in, const int* in_sizes, int n_in,
                              void* d_out, int out_size, void* d_ws, size_t ws_size,
                              hipStream_t stream) {
  (void)n_in; (void)out_size; (void)ws_size;
  int off = (in_sizes[1] == 1) ? 0 : -1;
  const float* hidden   = (const float*)d_in[0];
  const float* cosb     = (const float*)d_in[2 + off];
  const float* sinb     = (const float*)d_in[3 + off];
  const float* w_q      = (const float*)d_in[5 + off];
  const float* w_k      = (const float*)d_in[6 + off];
  const float* w_v      = (const float*)d_in[7 + off];
  const float* w_o      = (const float*)d_in[8 + off];
  const float* q_norm_w = (const float*)d_in[9 + off];
  const float* k_norm_w = (const float*)d_in[10 + off];
  const float* ln1_w    = (const float*)d_in[11 + off];
  const float* ln2_w    = (const float*)d_in[12 + off];
  const float* gate_w   = (const float*)d_in[13 + off];
  const float* w_gate_e = (const float*)d_in[14 + off];
  const float* w_up_e   = (const float*)d_in[15 + off];
  const float* w_down_e = (const float*)d_in[16 + off];
  float* F = (float*)d_out;             // fp32 output == residual accumulator
  int cosBS = in_sizes[2 + off] / cHD;  // 2048 if (B,S,HD)

  float* ws = (float*)d_ws;
  float* xbuf  = ws;                        // cT*cH (16MB): ln1 out -> ln2 out
  float* qcbuf = xbuf + (size_t)cT * cH;    // cT*cDq (16MB): q -> ctx -> act
  float* kbuf  = qcbuf + (size_t)cT * cDq;  // cT*cDkv (4MB)
  float* vbuf  = kbuf + (size_t)cT * cDkv;  // cT*cDkv (4MB)
  float* topw  = vbuf + (size_t)cT * cDkv;  // cT*2
  int* counts  = (int*)(topw + (size_t)cT * 2);
  int* lists   = counts + cE;               // cE*cT
  float* act   = qcbuf;                     // reuse after O-proj consumed ctx

  k_rmsnorm<<<cT, 256, 0, stream>>>(hidden, ln1_w, xbuf);
  k_sgemm_qkv<<<dim3((cDq + 2 * cDkv) / 128, cT / 128), 256, 0, stream>>>(
      xbuf, w_q, w_k, w_v, qcbuf, kbuf, vbuf);
  k_qknorm_rope<<<dim3(cT, cNH + cNKV), 128, 0, stream>>>(
      qcbuf, kbuf, q_norm_w, k_norm_w, cosb, sinb, cosBS);
  k_attn_tiled<<<dim3(cQT / 2, cNH, cB), 256, 0, stream>>>(qcbuf, kbuf, vbuf);
  k_sgemm_o<<<dim3(cH / 128, cT / 128), 256, 0, stream>>>(
      qcbuf, w_o, F, hidden);
  k_rmsnorm<<<cT, 256, 0, stream>>>(F, ln2_w, xbuf);
  k_zero_counts<<<1, 64, 0, stream>>>(counts);
  k_route<<<cT, 64, 0, stream>>>(xbuf, gate_w, topw, counts, lists);
  k_mfma_gateup<<<dim3(cI / 128, cT / 128, cE), 256, 0, stream>>>(
      xbuf, w_gate_e, w_up_e, counts, lists, topw, act);
  k_mfma_down<<<dim3(cH / 128, cT / 128, cE), 256, 0, stream>>>(
      act, w_down_e, counts, lists, F);
}

// Round 6
// 1000.240 us; speedup vs baseline: 3.0051x; 1.0107x over previous
//
#include <hip/hip_runtime.h>

// Qwen3 MoE decoder layer, MI355X. Round 11: attention de-latency pass.
// R10 counters: attn 300us, VALUBusy 35%, Occupancy 11.5% (grid 256 = 1
// block/CU), 16 shfl/kc in PV ~= the FMA cost. Changes (fp32 math kept,
// router-safe): (1) P broadcast via 16KB LDS Ps (written with V under the
// same barrier) instead of 16 ds_bpermute per kc; (2) 512 blocks with
// complement-qt mapping (CU gets qt and 15-qt -> 17 k-tiles/CU) at 80KB
// LDS = 2 blocks/CU. All other kernels byte-identical to the 1011-us R10.

namespace {

constexpr int cB = 2, cS = 1024, cH = 2048;
constexpr int cNH = 16, cNKV = 4, cHD = 128;
constexpr int cE = 8, cI = 768;
constexpr int cT = cB * cS;        // 2048 tokens
constexpr int cDq = cNH * cHD;     // 2048
constexpr int cDkv = cNKV * cHD;   // 512
constexpr float cEPS = 1e-6f;
constexpr float cSCALE = 0.08838834764831845f;  // HD^-0.5
constexpr int cQT = cS / 64;       // 16 q-tiles per (b,h)

typedef __attribute__((ext_vector_type(8))) short bf16x8;
typedef __attribute__((ext_vector_type(4))) float f32x4;

// fp32 -> bf16 round-to-nearest-even, packed pair (f0 low, f1 high)
__device__ __forceinline__ unsigned pack2(float f0, float f1) {
  unsigned u0 = __float_as_uint(f0), u1 = __float_as_uint(f1);
  unsigned r0 = (u0 + (0x7FFFu + ((u0 >> 16) & 1u))) >> 16;
  unsigned r1 = (u1 + (0x7FFFu + ((u1 >> 16) & 1u))) & 0xFFFF0000u;
  return r0 | r1;
}
__device__ __forceinline__ uint4 pack8(const float4& a, const float4& b) {
  return make_uint4(pack2(a.x, a.y), pack2(a.z, a.w),
                    pack2(b.x, b.y), pack2(b.z, b.w));
}

// truncating split helpers (Dekker-style two-term bf16 decomposition)
__device__ __forceinline__ unsigned pack2t(float f0, float f1) {
  return (__float_as_uint(f0) >> 16) | (__float_as_uint(f1) & 0xFFFF0000u);
}
__device__ __forceinline__ float hi_of(float f) {
  return __uint_as_float(__float_as_uint(f) & 0xFFFF0000u);
}
__device__ __forceinline__ void split8(const float4& x, const float4& y,
                                       uint4& h, uint4& l) {
  h = make_uint4(pack2t(x.x, x.y), pack2t(x.z, x.w),
                 pack2t(y.x, y.y), pack2t(y.z, y.w));
  float l0 = x.x - hi_of(x.x), l1 = x.y - hi_of(x.y);
  float l2 = x.z - hi_of(x.z), l3 = x.w - hi_of(x.w);
  float l4 = y.x - hi_of(y.x), l5 = y.y - hi_of(y.y);
  float l6 = y.z - hi_of(y.z), l7 = y.w - hi_of(y.w);
  l = make_uint4(pack2t(l0, l1), pack2t(l2, l3), pack2t(l4, l5), pack2t(l6, l7));
}

// ---------------- RMSNorm (fp32) ----------------
__global__ __launch_bounds__(256) void k_rmsnorm(
    const float* __restrict__ xin, const float* __restrict__ w,
    float* __restrict__ y) {
  int t = blockIdx.x, tid = threadIdx.x;
  __shared__ float red[256];
  const float* xr = xin + (size_t)t * cH;
  float xv[8];
  float ss = 0.f;
#pragma unroll
  for (int i = 0; i < 8; ++i) {
    xv[i] = xr[tid + i * 256];
    ss += xv[i] * xv[i];
  }
  red[tid] = ss;
  __syncthreads();
  for (int s = 128; s > 0; s >>= 1) {
    if (tid < s) red[tid] += red[tid + s];
    __syncthreads();
  }
  float inv = rsqrtf(red[0] / (float)cH + cEPS);
#pragma unroll
  for (int i = 0; i < 8; ++i)
    y[(size_t)t * cH + tid + i * 256] = xv[i] * inv * w[tid + i * 256];
}

// ---- split-bf16 3-pass MFMA GEMM core (128x128 tile, BK=32, 256 thr) ------
// C[m,n] = sum_k A[m,k]*W[n,k], error ~2^-16 relative (routing-safe).
#define SGEMM_BODY(APTR_EXPR, WPTR_EXPR, KDIM, EPILOGUE)                      \
  __shared__ __align__(16) short Ah[128 * 32];                                \
  __shared__ __align__(16) short Al[128 * 32];                                \
  __shared__ __align__(16) short Bh[128 * 32];                                \
  __shared__ __align__(16) short Bl[128 * 32];                                \
  int tid = threadIdx.x;                                                      \
  int sdst[2];                                                                \
  const float* aptr[2];                                                       \
  const float* wptr[2];                                                       \
  _Pragma("unroll") for (int b2 = 0; b2 < 2; ++b2) {                          \
    int bid = tid + b2 * 256;                                                 \
    int row = bid >> 2, blk = bid & 3;                                        \
    sdst[b2] = row * 4 + (blk ^ ((row >> 1) & 3));                            \
    aptr[b2] = (APTR_EXPR) + blk * 8;                                         \
    wptr[b2] = (WPTR_EXPR) + blk * 8;                                         \
  }                                                                           \
  int w = tid >> 6, l = tid & 63;                                             \
  int wr = (w >> 1) * 64, wc = (w & 1) * 64;                                  \
  int sub = l >> 4, l16 = l & 15;                                             \
  int offA[4], offB[4];                                                       \
  _Pragma("unroll") for (int i = 0; i < 4; ++i) {                             \
    int ra = wr + i * 16 + l16;                                               \
    offA[i] = ra * 4 + (sub ^ ((ra >> 1) & 3));                               \
    int rb = wc + i * 16 + l16;                                               \
    offB[i] = rb * 4 + (sub ^ ((rb >> 1) & 3));                               \
  }                                                                           \
  f32x4 acc[4][4] = {};                                                       \
  uint4* Ah4 = (uint4*)Ah;                                                    \
  uint4* Al4 = (uint4*)Al;                                                    \
  uint4* Bh4 = (uint4*)Bh;                                                    \
  uint4* Bl4 = (uint4*)Bl;                                                    \
  const bf16x8* Ahf = (const bf16x8*)Ah;                                      \
  const bf16x8* Alf = (const bf16x8*)Al;                                      \
  const bf16x8* Bhf = (const bf16x8*)Bh;                                      \
  const bf16x8* Blf = (const bf16x8*)Bl;                                      \
  for (int k0 = 0; k0 < (KDIM); k0 += 32) {                                   \
    float4 av0[2], av1[2], wv0[2], wv1[2];                                    \
    _Pragma("unroll") for (int b2 = 0; b2 < 2; ++b2) {                        \
      av0[b2] = *(const float4*)(aptr[b2] + k0);                              \
      av1[b2] = *(const float4*)(aptr[b2] + k0 + 4);                          \
      wv0[b2] = *(const float4*)(wptr[b2] + k0);                              \
      wv1[b2] = *(const float4*)(wptr[b2] + k0 + 4);                          \
    }                                                                         \
    __syncthreads();                                                          \
    _Pragma("unroll") for (int b2 = 0; b2 < 2; ++b2) {                        \
      uint4 h, lo;                                                            \
      split8(av0[b2], av1[b2], h, lo);                                        \
      Ah4[sdst[b2]] = h;                                                      \
      Al4[sdst[b2]] = lo;                                                     \
      split8(wv0[b2], wv1[b2], h, lo);                                        \
      Bh4[sdst[b2]] = h;                                                      \
      Bl4[sdst[b2]] = lo;                                                     \
    }                                                                         \
    __syncthreads();                                                          \
    bf16x8 ah[4], al[4], bh[4], bl[4];                                        \
    _Pragma("unroll") for (int i = 0; i < 4; ++i) {                           \
      ah[i] = Ahf[offA[i]];                                                   \
      al[i] = Alf[offA[i]];                                                   \
    }                                                                         \
    _Pragma("unroll") for (int j = 0; j < 4; ++j) {                           \
      bh[j] = Bhf[offB[j]];                                                   \
      bl[j] = Blf[offB[j]];                                                   \
    }                                                                         \
    _Pragma("unroll") for (int i = 0; i < 4; ++i)                             \
        _Pragma("unroll") for (int j = 0; j < 4; ++j) {                       \
      acc[i][j] = __builtin_amdgcn_mfma_f32_16x16x32_bf16(ah[i], bh[j],       \
                                                          acc[i][j], 0, 0, 0);\
      acc[i][j] = __builtin_amdgcn_mfma_f32_16x16x32_bf16(al[i], bh[j],       \
                                                          acc[i][j], 0, 0, 0);\
      acc[i][j] = __builtin_amdgcn_mfma_f32_16x16x32_bf16(ah[i], bl[j],       \
                                                          acc[i][j], 0, 0, 0);\
    }                                                                         \
  }                                                                           \
  _Pragma("unroll") for (int i = 0; i < 4; ++i) {                             \
    _Pragma("unroll") for (int rr = 0; rr < 4; ++rr) {                        \
      int lr = wr + i * 16 + sub * 4 + rr;                                    \
      _Pragma("unroll") for (int j = 0; j < 4; ++j) {                         \
        int nn = wc + j * 16 + l16;                                           \
        float vv = acc[i][j][rr];                                             \
        EPILOGUE;                                                             \
      }                                                                       \
    }                                                                         \
  }

// Fused QKV: A = ln1(x); n-tiles 0..15 -> q, 16..19 -> k, 20..23 -> v.
__global__ __launch_bounds__(256, 2) void k_sgemm_qkv(
    const float* __restrict__ A, const float* __restrict__ Wq,
    const float* __restrict__ Wk, const float* __restrict__ Wv,
    float* __restrict__ Cq, float* __restrict__ Ck, float* __restrict__ Cv) {
  int nBase = blockIdx.x * 128;
  int mBase = blockIdx.y * 128;
  const float* W;
  float* C;
  int Nout, ncol;
  if (nBase < cDq) {
    W = Wq; C = Cq; Nout = cDq; ncol = nBase;
  } else if (nBase < cDq + cDkv) {
    W = Wk; C = Ck; Nout = cDkv; ncol = nBase - cDq;
  } else {
    W = Wv; C = Cv; Nout = cDkv; ncol = nBase - cDq - cDkv;
  }
  SGEMM_BODY(A + (size_t)(mBase + row) * cH,
             W + (size_t)(ncol + row) * cH, cH,
             C[(size_t)(mBase + lr) * Nout + ncol + nn] = vv)
}

// O-projection + residual: F = ctx @ w_o^T + hidden
__global__ __launch_bounds__(256, 2) void k_sgemm_o(
    const float* __restrict__ A, const float* __restrict__ W,
    float* __restrict__ C, const float* __restrict__ resid) {
  int nBase = blockIdx.x * 128;
  int mBase = blockIdx.y * 128;
  SGEMM_BODY(A + (size_t)(mBase + row) * cH,
             W + (size_t)(nBase + row) * cH, cH,
             {
               size_t idx = (size_t)(mBase + lr) * cH + nBase + nn;
               C[idx] = vv + resid[idx];
             })
}

// ---------------- per-head RMSNorm + RoPE on q and k (in place) ------------
__global__ __launch_bounds__(128) void k_qknorm_rope(
    float* qbuf, float* kbuf,
    const float* __restrict__ qw, const float* __restrict__ kw,
    const float* __restrict__ cosb, const float* __restrict__ sinb,
    int cosBS) {
  int t = blockIdx.x, head = blockIdx.y, d = threadIdx.x;
  float* buf;
  const float* w;
  if (head < cNH) {
    buf = qbuf + (size_t)t * cDq + head * cHD;
    w = qw;
  } else {
    buf = kbuf + (size_t)t * cDkv + (head - cNH) * cHD;
    w = kw;
  }
  __shared__ float xs[cHD];
  __shared__ float red[cHD];
  float x = buf[d];
  xs[d] = x;
  red[d] = x * x;
  __syncthreads();
  for (int s = 64; s > 0; s >>= 1) {
    if (d < s) red[d] += red[d + s];
    __syncthreads();
  }
  float inv = rsqrtf(red[0] / (float)cHD + cEPS);
  int od = d ^ 64;  // rotate_half partner
  float y = x * inv * w[d];
  float yo = xs[od] * inv * w[od];
  float rot = (d < 64) ? -yo : yo;
  size_t ci = (size_t)(t % cosBS) * cHD + d;
  buf[d] = y * cosb[ci] + rot * sinb[ci];
}

// ---------------- tiled causal attention (fp32, online softmax) ------------
// 512 blocks, one 64-row q-tile each. Complement-qt mapping: bid<256 ->
// qt=bid>>5, else qt=15-((bid-256)>>5) -- round-robin CU assignment gives
// each CU qt + (15-qt) = 17 k-tiles. LDS 80KB -> 2 blocks/CU (8 waves).
// P broadcast via Ps LDS (written with V under one barrier), no shfl.
__device__ __forceinline__ int swzKQ(int r, int cb) {  // cb: float4 block 0..31
  return r * 128 + ((cb ^ ((r >> 2) & 7)) << 2);
}
__device__ __forceinline__ int swzP(int r, int cb) {   // cb: float4 block 0..15
  return r * 64 + ((cb ^ ((r >> 2) & 7)) << 2);
}

__global__ __launch_bounds__(256) void k_attn_tiled(
    float* qc, const float* __restrict__ k, const float* __restrict__ v) {
  __shared__ __align__(16) float Qs[64 * 128];   // 32 KB
  __shared__ __align__(16) float KVs[64 * 128];  // 32 KB, K then V per tile
  __shared__ __align__(16) float Ps[64 * 64];    // 16 KB
  int bid = blockIdx.x;
  int qt, rest;
  if (bid < 256) {
    qt = bid >> 5;
    rest = bid & 31;
  } else {
    int r2 = bid - 256;
    qt = 15 - (r2 >> 5);
    rest = r2 & 31;
  }
  int h = rest >> 1, b = rest & 1;
  int kvh = h >> 2;  // rep = NH/NKV = 4
  int tid = threadIdx.x;
  int tx = tid & 15, ty = tid >> 4;
  const float* kbase = k + (size_t)b * cS * cDkv + kvh * cHD;
  const float* vbase = v + (size_t)b * cS * cDkv + kvh * cHD;
  float* qhbase = qc + (size_t)b * cS * cDq + h * cHD;

  // ---- load Q tile (scaled) into swizzled LDS ----
#pragma unroll
  for (int ch = 0; ch < 8; ++ch) {
    int idx = tid + ch * 256;
    int r = idx >> 5, cb = idx & 31;
    float4 qv = *(const float4*)(qhbase + (size_t)(qt * 64 + r) * cDq + cb * 4);
    qv.x *= cSCALE; qv.y *= cSCALE; qv.z *= cSCALE; qv.w *= cSCALE;
    *(float4*)&Qs[swzKQ(r, cb)] = qv;
  }
  // ---- prefetch K tile 0 into registers ----
  float4 kreg[8];
#pragma unroll
  for (int ch = 0; ch < 8; ++ch) {
    int idx = tid + ch * 256;
    int r = idx >> 5, cb = idx & 31;
    kreg[ch] = *(const float4*)(kbase + (size_t)r * cDkv + cb * 4);
  }
  float m[4], l[4], O[4][8];
#pragma unroll
  for (int i = 0; i < 4; ++i) {
    m[i] = -1e30f;
    l[i] = 0.f;
#pragma unroll
    for (int j = 0; j < 8; ++j) O[i][j] = 0.f;
  }
  __syncthreads();  // Qs visible

  for (int kt = 0; kt <= qt; ++kt) {
    // ---- K tile: registers -> LDS ----
#pragma unroll
    for (int ch = 0; ch < 8; ++ch) {
      int idx = tid + ch * 256;
      *(float4*)&KVs[swzKQ(idx >> 5, idx & 31)] = kreg[ch];
    }
    __syncthreads();
    // ---- issue V loads now; consumed after QK^T (latency hidden) ----
    float4 vreg[8];
#pragma unroll
    for (int ch = 0; ch < 8; ++ch) {
      int idx = tid + ch * 256;
      int r = idx >> 5, cb = idx & 31;
      vreg[ch] = *(const float4*)(vbase + (size_t)(kt * 64 + r) * cDkv + cb * 4);
    }
    // ---- S = Q K^T (4x4 per thread) ----
    float acc[4][4] = {};
#pragma unroll 8
    for (int dblk = 0; dblk < 32; ++dblk) {
      float4 a4[4], b4[4];
#pragma unroll
      for (int i = 0; i < 4; ++i)
        a4[i] = *(const float4*)&Qs[swzKQ(ty * 4 + i, dblk)];
#pragma unroll
      for (int j = 0; j < 4; ++j)
        b4[j] = *(const float4*)&KVs[swzKQ(tx * 4 + j, dblk)];
#pragma unroll
      for (int i = 0; i < 4; ++i)
#pragma unroll
        for (int j = 0; j < 4; ++j)
          acc[i][j] += a4[i].x * b4[j].x + a4[i].y * b4[j].y +
                       a4[i].z * b4[j].z + a4[i].w * b4[j].w;
    }
    // ---- causal mask: only the diagonal tile has masked entries ----
    if (kt == qt) {
#pragma unroll
      for (int i = 0; i < 4; ++i)
#pragma unroll
        for (int j = 0; j < 4; ++j)
          if (tx * 4 + j > ty * 4 + i) acc[i][j] = -1e30f;
    }
    // ---- online softmax update (row stats via 16-lane butterflies) ----
    float ps[4][4];
#pragma unroll
    for (int i = 0; i < 4; ++i) {
      float rm = fmaxf(fmaxf(acc[i][0], acc[i][1]), fmaxf(acc[i][2], acc[i][3]));
#pragma unroll
      for (int msk = 1; msk < 16; msk <<= 1) rm = fmaxf(rm, __shfl_xor(rm, msk));
      float nm = fmaxf(m[i], rm);
      float sc_ = __expf(m[i] - nm);  // m=-1e30 first pass -> 0
      float rs = 0.f;
#pragma unroll
      for (int j = 0; j < 4; ++j) {
        ps[i][j] = __expf(acc[i][j] - nm);
        rs += ps[i][j];
      }
#pragma unroll
      for (int msk = 1; msk < 16; msk <<= 1) rs += __shfl_xor(rs, msk);
      l[i] = l[i] * sc_ + rs;
      m[i] = nm;
#pragma unroll
      for (int j = 0; j < 8; ++j) O[i][j] *= sc_;
    }
    __syncthreads();  // all QK^T reads of KVs (=K) done
    // ---- V tile + P tile -> LDS (one barrier covers both) ----
#pragma unroll
    for (int ch = 0; ch < 8; ++ch) {
      int idx = tid + ch * 256;
      *(float4*)&KVs[swzKQ(idx >> 5, idx & 31)] = vreg[ch];
    }
#pragma unroll
    for (int i = 0; i < 4; ++i)
      *(float4*)&Ps[swzP(ty * 4 + i, tx)] =
          make_float4(ps[i][0], ps[i][1], ps[i][2], ps[i][3]);
    __syncthreads();
    // ---- prefetch next K tile; latency hidden under PV ----
    if (kt < qt) {
#pragma unroll
      for (int ch = 0; ch < 8; ++ch) {
        int idx = tid + ch * 256;
        int r = idx >> 5, cb = idx & 31;
        kreg[ch] =
            *(const float4*)(kbase + (size_t)((kt + 1) * 64 + r) * cDkv + cb * 4);
      }
    }
    // ---- O += P V; P broadcast from LDS (16-lane groups share addr) ----
#pragma unroll 4
    for (int kc = 0; kc < 16; ++kc) {
      float4 p4[4];
#pragma unroll
      for (int i = 0; i < 4; ++i)
        p4[i] = *(const float4*)&Ps[swzP(ty * 4 + i, kc)];
      float pv_[4][4];
#pragma unroll
      for (int i = 0; i < 4; ++i) {
        pv_[i][0] = p4[i].x; pv_[i][1] = p4[i].y;
        pv_[i][2] = p4[i].z; pv_[i][3] = p4[i].w;
      }
#pragma unroll
      for (int q = 0; q < 4; ++q) {
        int kk = kc * 4 + q;
        float4 va = *(const float4*)&KVs[swzKQ(kk, tx)];
        float4 vb = *(const float4*)&KVs[swzKQ(kk, tx + 16)];
#pragma unroll
        for (int i = 0; i < 4; ++i) {
          float pq = pv_[i][q];
          O[i][0] += pq * va.x; O[i][1] += pq * va.y;
          O[i][2] += pq * va.z; O[i][3] += pq * va.w;
          O[i][4] += pq * vb.x; O[i][5] += pq * vb.y;
          O[i][6] += pq * vb.z; O[i][7] += pq * vb.w;
        }
      }
    }
    __syncthreads();  // PV reads of KVs/Ps done before next K/P write
  }  // kt
  // ---- epilogue: ctx = O / l, written back in place over q ----
#pragma unroll
  for (int i = 0; i < 4; ++i) {
    float inv = 1.f / l[i];
    float* orow = qhbase + (size_t)(qt * 64 + ty * 4 + i) * cDq;
    *(float4*)(orow + tx * 4) =
        make_float4(O[i][0] * inv, O[i][1] * inv, O[i][2] * inv, O[i][3] * inv);
    *(float4*)(orow + 64 + tx * 4) =
        make_float4(O[i][4] * inv, O[i][5] * inv, O[i][6] * inv, O[i][7] * inv);
  }
}

// ---------------- router: logits, top-2, compaction ------------------------
__global__ void k_zero_counts(int* __restrict__ counts) {
  if (threadIdx.x < cE) counts[threadIdx.x] = 0;
}

__global__ __launch_bounds__(64) void k_route(
    const float* __restrict__ x2, const float* __restrict__ gw,
    float* __restrict__ topw, int* __restrict__ counts, int* __restrict__ lists) {
  int t = blockIdx.x, lane = threadIdx.x;
  float acc[cE];
#pragma unroll
  for (int e = 0; e < cE; ++e) acc[e] = 0.f;
  const float* xr = x2 + (size_t)t * cH;
  for (int hh = lane; hh < cH; hh += 64) {
    float xv = xr[hh];
#pragma unroll
    for (int e = 0; e < cE; ++e) acc[e] += xv * gw[e * cH + hh];
  }
#pragma unroll
  for (int e = 0; e < cE; ++e)
    for (int off = 32; off > 0; off >>= 1) acc[e] += __shfl_down(acc[e], off);
  if (lane == 0) {
    int i0 = 0;
    float l0 = acc[0];
#pragma unroll
    for (int e = 1; e < cE; ++e)
      if (acc[e] > l0) { l0 = acc[e]; i0 = e; }
    int i1 = -1;
    float l1 = -1e30f;
#pragma unroll
    for (int e = 0; e < cE; ++e)
      if (e != i0 && acc[e] > l1) { l1 = acc[e]; i1 = e; }
    if (i1 < 0) { i1 = (i0 + 1) & 7; l1 = l0; }  // NaN-safe
    float r = expf(l1 - l0);  // top-2 softmax renorm == sigmoid of gap
    topw[t * 2 + 0] = 1.f / (1.f + r);
    topw[t * 2 + 1] = r / (1.f + r);
    int p0 = atomicAdd(&counts[i0], 1);
    lists[i0 * cT + p0] = t * 2;      // entry = token*2 + slot
    int p1 = atomicAdd(&counts[i1], 1);
    lists[i1 * cT + p1] = t * 2 + 1;
  }
}

// ------- fused MoE gate+up MFMA GEMM + SiLU*up*route-weight -> act ---------
__global__ __launch_bounds__(256, 2) void k_mfma_gateup(
    const float* __restrict__ X, const float* __restrict__ Wg,
    const float* __restrict__ Wu, const int* __restrict__ counts,
    const int* __restrict__ lists, const float* __restrict__ topw,
    float* __restrict__ act) {
  int e = blockIdx.z;
  int cnt = counts[e];
  int mBase = blockIdx.y * 128;
  if (mBase >= cnt) return;
  int nBase = blockIdx.x * 128;
  __shared__ __align__(16) short As[128 * 32];
  __shared__ __align__(16) short Gs[128 * 32];
  __shared__ __align__(16) short Us[128 * 32];
  __shared__ int rowE[128];
  int tid = threadIdx.x;
  if (tid < 128) {
    int r = mBase + tid;
    rowE[tid] = (r < cnt) ? lists[e * cT + r] : -1;
  }
  __syncthreads();
  const float* gbase = Wg + (size_t)e * cI * cH;
  const float* ubase = Wu + (size_t)e * cI * cH;
  int sdst[2];
  const float* aptr[2];
  const float* gptr[2];
  const float* uptr[2];
#pragma unroll
  for (int b2 = 0; b2 < 2; ++b2) {
    int bid = tid + b2 * 256;
    int row = bid >> 2, blk = bid & 3;
    sdst[b2] = row * 4 + (blk ^ ((row >> 1) & 3));
    int ent = rowE[row];
    int arow = (ent < 0) ? 0 : (ent >> 1);
    aptr[b2] = X + (size_t)arow * cH + blk * 8;
    gptr[b2] = gbase + (size_t)(nBase + row) * cH + blk * 8;
    uptr[b2] = ubase + (size_t)(nBase + row) * cH + blk * 8;
  }
  int w = tid >> 6, l = tid & 63;
  int wr = (w >> 1) * 64, wc = (w & 1) * 64;
  int sub = l >> 4, l16 = l & 15;
  int offA[4], offB[4];
#pragma unroll
  for (int i = 0; i < 4; ++i) {
    int ra = wr + i * 16 + l16;
    offA[i] = ra * 4 + (sub ^ ((ra >> 1) & 3));
    int rb = wc + i * 16 + l16;
    offB[i] = rb * 4 + (sub ^ ((rb >> 1) & 3));
  }
  f32x4 accg[4][4] = {}, accu[4][4] = {};
  uint4* As4 = (uint4*)As;
  uint4* Gs4 = (uint4*)Gs;
  uint4* Us4 = (uint4*)Us;
  const bf16x8* Af = (const bf16x8*)As;
  const bf16x8* Gf = (const bf16x8*)Gs;
  const bf16x8* Uf = (const bf16x8*)Us;
  for (int k0 = 0; k0 < cH; k0 += 32) {
    float4 av0[2], av1[2], gv0[2], gv1[2], uv0[2], uv1[2];
#pragma unroll
    for (int b2 = 0; b2 < 2; ++b2) {
      av0[b2] = *(const float4*)(aptr[b2] + k0);
      av1[b2] = *(const float4*)(aptr[b2] + k0 + 4);
      gv0[b2] = *(const float4*)(gptr[b2] + k0);
      gv1[b2] = *(const float4*)(gptr[b2] + k0 + 4);
      uv0[b2] = *(const float4*)(uptr[b2] + k0);
      uv1[b2] = *(const float4*)(uptr[b2] + k0 + 4);
    }
    __syncthreads();  // previous iteration's frag reads done
#pragma unroll
    for (int b2 = 0; b2 < 2; ++b2) {
      As4[sdst[b2]] = pack8(av0[b2], av1[b2]);
      Gs4[sdst[b2]] = pack8(gv0[b2], gv1[b2]);
      Us4[sdst[b2]] = pack8(uv0[b2], uv1[b2]);
    }
    __syncthreads();  // staged tile visible
    bf16x8 af[4];
#pragma unroll
    for (int i = 0; i < 4; ++i) af[i] = Af[offA[i]];
#pragma unroll
    for (int j = 0; j < 4; ++j) {
      bf16x8 bg = Gf[offB[j]];
      bf16x8 bu = Uf[offB[j]];
#pragma unroll
      for (int i = 0; i < 4; ++i) {
        accg[i][j] = __builtin_amdgcn_mfma_f32_16x16x32_bf16(
            af[i], bg, accg[i][j], 0, 0, 0);
        accu[i][j] = __builtin_amdgcn_mfma_f32_16x16x32_bf16(
            af[i], bu, accu[i][j], 0, 0, 0);
      }
    }
  }
  // C/D layout (verified): col = lane&15, row = (lane>>4)*4 + reg
#pragma unroll
  for (int i = 0; i < 4; ++i) {
#pragma unroll
    for (int rr = 0; rr < 4; ++rr) {
      int lr = wr + i * 16 + sub * 4 + rr;
      int ent = rowE[lr];
      if (ent < 0) continue;
      float wgt = topw[ent];
#pragma unroll
      for (int j = 0; j < 4; ++j) {
        int n = nBase + wc + j * 16 + l16;
        float g = accg[i][j][rr], u = accu[i][j][rr];
        float sg = g / (1.f + __expf(-g));
        act[(size_t)ent * cI + n] = sg * u * wgt;
      }
    }
  }
}

// ------- MoE down MFMA GEMM, gather act rows, atomicAdd into F -------------
__global__ __launch_bounds__(256, 2) void k_mfma_down(
    const float* __restrict__ act, const float* __restrict__ Wd,
    const int* __restrict__ counts, const int* __restrict__ lists,
    float* __restrict__ F) {
  int e = blockIdx.z;
  int cnt = counts[e];
  int mBase = blockIdx.y * 128;
  if (mBase >= cnt) return;
  int nBase = blockIdx.x * 128;
  __shared__ __align__(16) short As[128 * 32];
  __shared__ __align__(16) short Bs[128 * 32];
  __shared__ int rowE[128];
  int tid = threadIdx.x;
  if (tid < 128) {
    int r = mBase + tid;
    rowE[tid] = (r < cnt) ? lists[e * cT + r] : -1;
  }
  __syncthreads();
  const float* wbase = Wd + (size_t)e * cH * cI;
  int sdst[2];
  const float* aptr[2];
  const float* wptr[2];
#pragma unroll
  for (int b2 = 0; b2 < 2; ++b2) {
    int bid = tid + b2 * 256;
    int row = bid >> 2, blk = bid & 3;
    sdst[b2] = row * 4 + (blk ^ ((row >> 1) & 3));
    int ent = rowE[row];
    int arow = (ent < 0) ? 0 : ent;
    aptr[b2] = act + (size_t)arow * cI + blk * 8;
    wptr[b2] = wbase + (size_t)(nBase + row) * cI + blk * 8;
  }
  int w = tid >> 6, l = tid & 63;
  int wr = (w >> 1) * 64, wc = (w & 1) * 64;
  int sub = l >> 4, l16 = l & 15;
  int offA[4], offB[4];
#pragma unroll
  for (int i = 0; i < 4; ++i) {
    int ra = wr + i * 16 + l16;
    offA[i] = ra * 4 + (sub ^ ((ra >> 1) & 3));
    int rb = wc + i * 16 + l16;
    offB[i] = rb * 4 + (sub ^ ((rb >> 1) & 3));
  }
  f32x4 acc[4][4] = {};
  uint4* As4 = (uint4*)As;
  uint4* Bs4 = (uint4*)Bs;
  const bf16x8* Af = (const bf16x8*)As;
  const bf16x8* Bf = (const bf16x8*)Bs;
  for (int k0 = 0; k0 < cI; k0 += 32) {
    float4 av0[2], av1[2], wv0[2], wv1[2];
#pragma unroll
    for (int b2 = 0; b2 < 2; ++b2) {
      av0[b2] = *(const float4*)(aptr[b2] + k0);
      av1[b2] = *(const float4*)(aptr[b2] + k0 + 4);
      wv0[b2] = *(const float4*)(wptr[b2] + k0);
      wv1[b2] = *(const float4*)(wptr[b2] + k0 + 4);
    }
    __syncthreads();
#pragma unroll
    for (int b2 = 0; b2 < 2; ++b2) {
      As4[sdst[b2]] = pack8(av0[b2], av1[b2]);
      Bs4[sdst[b2]] = pack8(wv0[b2], wv1[b2]);
    }
    __syncthreads();
    bf16x8 af[4], bfr[4];
#pragma unroll
    for (int i = 0; i < 4; ++i) af[i] = Af[offA[i]];
#pragma unroll
    for (int j = 0; j < 4; ++j) bfr[j] = Bf[offB[j]];
#pragma unroll
    for (int i = 0; i < 4; ++i)
#pragma unroll
      for (int j = 0; j < 4; ++j)
        acc[i][j] = __builtin_amdgcn_mfma_f32_16x16x32_bf16(
            af[i], bfr[j], acc[i][j], 0, 0, 0);
  }
#pragma unroll
  for (int i = 0; i < 4; ++i) {
#pragma unroll
    for (int rr = 0; rr < 4; ++rr) {
      int lr = wr + i * 16 + sub * 4 + rr;
      int ent = rowE[lr];
      if (ent < 0) continue;
      int t = ent >> 1;
#pragma unroll
      for (int j = 0; j < 4; ++j) {
        int n = nBase + wc + j * 16 + l16;
        atomicAdd(&F[(size_t)t * cH + n], acc[i][j][rr]);
      }
    }
  }
}

}  // namespace

extern "C" void kernel_launch(void* const* d_in, const int* in_sizes, int n_in,
                              void* d_out, int out_size, void* d_ws, size_t ws_size,
                              hipStream_t stream) {
  (void)n_in; (void)out_size; (void)ws_size;
  int off = (in_sizes[1] == 1) ? 0 : -1;
  const float* hidden   = (const float*)d_in[0];
  const float* cosb     = (const float*)d_in[2 + off];
  const float* sinb     = (const float*)d_in[3 + off];
  const float* w_q      = (const float*)d_in[5 + off];
  const float* w_k      = (const float*)d_in[6 + off];
  const float* w_v      = (const float*)d_in[7 + off];
  const float* w_o      = (const float*)d_in[8 + off];
  const float* q_norm_w = (const float*)d_in[9 + off];
  const float* k_norm_w = (const float*)d_in[10 + off];
  const float* ln1_w    = (const float*)d_in[11 + off];
  const float* ln2_w    = (const float*)d_in[12 + off];
  const float* gate_w   = (const float*)d_in[13 + off];
  const float* w_gate_e = (const float*)d_in[14 + off];
  const float* w_up_e   = (const float*)d_in[15 + off];
  const float* w_down_e = (const float*)d_in[16 + off];
  float* F = (float*)d_out;             // fp32 output == residual accumulator
  int cosBS = in_sizes[2 + off] / cHD;  // 2048 if (B,S,HD)

  float* ws = (float*)d_ws;
  float* xbuf  = ws;                        // cT*cH (16MB): ln1 out -> ln2 out
  float* qcbuf = xbuf + (size_t)cT * cH;    // cT*cDq (16MB): q -> ctx -> act
  float* kbuf  = qcbuf + (size_t)cT * cDq;  // cT*cDkv (4MB)
  float* vbuf  = kbuf + (size_t)cT * cDkv;  // cT*cDkv (4MB)
  float* topw  = vbuf + (size_t)cT * cDkv;  // cT*2
  int* counts  = (int*)(topw + (size_t)cT * 2);
  int* lists   = counts + cE;               // cE*cT
  float* act   = qcbuf;                     // reuse after O-proj consumed ctx

  k_rmsnorm<<<cT, 256, 0, stream>>>(hidden, ln1_w, xbuf);
  k_sgemm_qkv<<<dim3((cDq + 2 * cDkv) / 128, cT / 128), 256, 0, stream>>>(
      xbuf, w_q, w_k, w_v, qcbuf, kbuf, vbuf);
  k_qknorm_rope<<<dim3(cT, cNH + cNKV), 128, 0, stream>>>(
      qcbuf, kbuf, q_norm_w, k_norm_w, cosb, sinb, cosBS);
  k_attn_tiled<<<2 * cQT * cNH * cB / 2, 256, 0, stream>>>(qcbuf, kbuf, vbuf);
  k_sgemm_o<<<dim3(cH / 128, cT / 128), 256, 0, stream>>>(
      qcbuf, w_o, F, hidden);
  k_rmsnorm<<<cT, 256, 0, stream>>>(F, ln2_w, xbuf);
  k_zero_counts<<<1, 64, 0, stream>>>(counts);
  k_route<<<cT, 64, 0, stream>>>(xbuf, gate_w, topw, counts, lists);
  k_mfma_gateup<<<dim3(cI / 128, cT / 128, cE), 256, 0, stream>>>(
      xbuf, w_gate_e, w_up_e, counts, lists, topw, act);
  k_mfma_down<<<dim3(cH / 128, cT / 128, cE), 256, 0, stream>>>(
      act, w_down_e, counts, lists, F);
}